// Round 2
// baseline (1410.429 us; speedup 1.0000x reference)
//
#include <hip/hip_runtime.h>
#include <hip/hip_bf16.h>
#include <math.h>

#define B_    2
#define T_    1024
#define DIM_  1024
#define H_    16
#define D_    64
#define M_    (B_ * T_)      // 2048 rows
#define NQKV_ 3072
#define NTOT_ 4096

// elu(x)+1 == exp(x) for x<=0, x+1 for x>0
__device__ __forceinline__ float elu1(float x) {
    return x > 0.f ? x + 1.f : expf(x);
}

// ---------------------------------------------------------------------------
// Kernel A: fused input GEMM  x(2048,1024) @ [w_qkv(1024,3072) | w_gate(1024,1024)]
// epilogue applies elu+1 (q,k), sigmoid (gate), and scatters to (B*T, H*D) bufs.
// Tile: BM=128, BN=64, BK=16, 256 threads, 8x4 micro-tile.
// ---------------------------------------------------------------------------
__global__ __launch_bounds__(256) void gemm_in(
    const float* __restrict__ x, const float* __restrict__ wqkv,
    const float* __restrict__ wgate, float* __restrict__ qp,
    float* __restrict__ kp, float* __restrict__ vp, float* __restrict__ gt) {
    __shared__ float As[16][128];
    __shared__ float Bs[16][64];
    const int tid = threadIdx.x;
    const int m0 = blockIdx.y * 128;
    const int n0 = blockIdx.x * 64;

    const float* wsrc;
    int wld, nc0;
    if (n0 < NQKV_) { wsrc = wqkv;  wld = NQKV_; nc0 = n0; }
    else            { wsrc = wgate; wld = DIM_;  nc0 = n0 - NQKV_; }

    const int tx = tid & 15;    // 16 col groups (4 cols each)
    const int ty = tid >> 4;    // 16 row groups (8 rows each)

    float acc[8][4];
#pragma unroll
    for (int i = 0; i < 8; ++i)
#pragma unroll
        for (int j = 0; j < 4; ++j) acc[i][j] = 0.f;

    const int ar = tid >> 2;        // 0..63
    const int ac = (tid & 3) * 4;   // 0,4,8,12
    const int br = tid >> 6;        // 0..3
    const int bc = tid & 63;

    for (int k0 = 0; k0 < DIM_; k0 += 16) {
#pragma unroll
        for (int rep = 0; rep < 2; ++rep) {
            float4 a = *(const float4*)&x[(size_t)(m0 + ar + rep * 64) * DIM_ + k0 + ac];
            As[ac + 0][ar + rep * 64] = a.x;
            As[ac + 1][ar + rep * 64] = a.y;
            As[ac + 2][ar + rep * 64] = a.z;
            As[ac + 3][ar + rep * 64] = a.w;
        }
#pragma unroll
        for (int rep = 0; rep < 4; ++rep) {
            Bs[br + rep * 4][bc] = wsrc[(size_t)(k0 + br + rep * 4) * wld + nc0 + bc];
        }
        __syncthreads();
#pragma unroll
        for (int kk = 0; kk < 16; ++kk) {
            float4 b4 = *(const float4*)&Bs[kk][tx * 4];
            float4 a0 = *(const float4*)&As[kk][ty * 8];
            float4 a1 = *(const float4*)&As[kk][ty * 8 + 4];
            float a[8] = {a0.x, a0.y, a0.z, a0.w, a1.x, a1.y, a1.z, a1.w};
            float b[4] = {b4.x, b4.y, b4.z, b4.w};
#pragma unroll
            for (int i = 0; i < 8; ++i)
#pragma unroll
                for (int j = 0; j < 4; ++j) acc[i][j] += a[i] * b[j];
        }
        __syncthreads();
    }

    // epilogue: activation + scatter
#pragma unroll
    for (int i = 0; i < 8; ++i) {
        int m = m0 + ty * 8 + i;
#pragma unroll
        for (int j = 0; j < 4; ++j) {
            int n = n0 + tx * 4 + j;
            float v = acc[i][j];
            if (n0 < NQKV_) {
                int s  = n >> 10;        // 0:q 1:k 2:v
                int hd = n & 1023;       // h*64+d
                size_t o = (size_t)m * 1024 + hd;
                if (s == 0)      qp[o] = elu1(v);
                else if (s == 1) kp[o] = elu1(v);
                else             vp[o] = v;
            } else {
                gt[(size_t)m * 1024 + (n - NQKV_)] = 1.f / (1.f + expf(-v));
            }
        }
    }
}

// ---------------------------------------------------------------------------
// Kernel B: causal linear attention per (b,h).
// num[t,i] = sum_{s<=t} (q_t . k_s) v[s,i];  den[t] = sum_{s<=t} (q_t . k_s)
// out = num/(den+1e-6) * gate, written in place over the gate buffer.
// One 64-thread wave per 64-row t-tile; lane owns one t (q row + 64 accs in
// regs); K/V s-tiles staged in LDS (pad 68 -> conflict-free broadcast reads).
// ---------------------------------------------------------------------------
__global__ __launch_bounds__(64) void attn(
    const float* __restrict__ qp, const float* __restrict__ kp,
    const float* __restrict__ vp, float* __restrict__ gt_att) {
    __shared__ float ks[64][68];
    __shared__ float vs[64][68];
    const int lane = threadIdx.x;         // t within tile
    const int tt   = blockIdx.x;          // t-tile
    const int h    = blockIdx.y;
    const int b    = blockIdx.z;
    const int t    = tt * 64 + lane;
    const size_t rowbase = (size_t)(b * T_ + t) * 1024 + h * 64;

    // stage q tile via LDS (coalesced global), then lane's row into regs
    float q[64];
#pragma unroll 4
    for (int r = 0; r < 64; ++r) {
        ks[r][lane] = qp[(size_t)(b * T_ + tt * 64 + r) * 1024 + h * 64 + lane];
    }
    __syncthreads();
#pragma unroll
    for (int d = 0; d < 64; ++d) q[d] = ks[lane][d];
    __syncthreads();

    float num[64];
#pragma unroll
    for (int i = 0; i < 64; ++i) num[i] = 0.f;
    float den = 0.f;

    for (int st = 0; st <= tt; ++st) {
        // stage K/V s-tile (coalesced 1KB per wave instruction)
        {
            const int c  = (lane & 15) * 4;
            const int r0 = lane >> 4;   // 0..3
#pragma unroll
            for (int rep = 0; rep < 16; ++rep) {
                int r = r0 + rep * 4;
                size_t g = (size_t)(b * T_ + st * 64 + r) * 1024 + h * 64 + c;
                *(float4*)&ks[r][c] = *(const float4*)&kp[g];
                *(float4*)&vs[r][c] = *(const float4*)&vp[g];
            }
        }
        __syncthreads();
        const int rmax = (st == tt) ? lane : 63;   // causal within diagonal
        for (int r = 0; r <= rmax; ++r) {
            float a = 0.f;
#pragma unroll
            for (int d4 = 0; d4 < 16; ++d4) {
                float4 kk = *(const float4*)&ks[r][d4 * 4];
                a += q[d4 * 4 + 0] * kk.x + q[d4 * 4 + 1] * kk.y +
                     q[d4 * 4 + 2] * kk.z + q[d4 * 4 + 3] * kk.w;
            }
            den += a;
#pragma unroll
            for (int i4 = 0; i4 < 16; ++i4) {
                float4 vv = *(const float4*)&vs[r][i4 * 4];
                num[i4 * 4 + 0] += a * vv.x;
                num[i4 * 4 + 1] += a * vv.y;
                num[i4 * 4 + 2] += a * vv.z;
                num[i4 * 4 + 3] += a * vv.w;
            }
        }
        __syncthreads();
    }

    const float inv = 1.f / (den + 1e-6f);
#pragma unroll
    for (int i4 = 0; i4 < 16; ++i4) {
        float4 g4 = *(const float4*)&gt_att[rowbase + i4 * 4];
        float4 o;
        o.x = num[i4 * 4 + 0] * inv * g4.x;
        o.y = num[i4 * 4 + 1] * inv * g4.y;
        o.z = num[i4 * 4 + 2] * inv * g4.z;
        o.w = num[i4 * 4 + 3] * inv * g4.w;
        *(float4*)&gt_att[rowbase + i4 * 4] = o;
    }
}

// ---------------------------------------------------------------------------
// Kernel C: output GEMM  att(2048,1024) @ w_out(1024,1024) -> out(2048,1024)
// ---------------------------------------------------------------------------
__global__ __launch_bounds__(256) void gemm_out(
    const float* __restrict__ att, const float* __restrict__ wout,
    float* __restrict__ out) {
    __shared__ float As[16][128];
    __shared__ float Bs[16][64];
    const int tid = threadIdx.x;
    const int m0 = blockIdx.y * 128;
    const int n0 = blockIdx.x * 64;
    const int tx = tid & 15;
    const int ty = tid >> 4;

    float acc[8][4];
#pragma unroll
    for (int i = 0; i < 8; ++i)
#pragma unroll
        for (int j = 0; j < 4; ++j) acc[i][j] = 0.f;

    const int ar = tid >> 2;
    const int ac = (tid & 3) * 4;
    const int br = tid >> 6;
    const int bc = tid & 63;

    for (int k0 = 0; k0 < DIM_; k0 += 16) {
#pragma unroll
        for (int rep = 0; rep < 2; ++rep) {
            float4 a = *(const float4*)&att[(size_t)(m0 + ar + rep * 64) * DIM_ + k0 + ac];
            As[ac + 0][ar + rep * 64] = a.x;
            As[ac + 1][ar + rep * 64] = a.y;
            As[ac + 2][ar + rep * 64] = a.z;
            As[ac + 3][ar + rep * 64] = a.w;
        }
#pragma unroll
        for (int rep = 0; rep < 4; ++rep) {
            Bs[br + rep * 4][bc] = wout[(size_t)(k0 + br + rep * 4) * DIM_ + n0 + bc];
        }
        __syncthreads();
#pragma unroll
        for (int kk = 0; kk < 16; ++kk) {
            float4 b4 = *(const float4*)&Bs[kk][tx * 4];
            float4 a0 = *(const float4*)&As[kk][ty * 8];
            float4 a1 = *(const float4*)&As[kk][ty * 8 + 4];
            float a[8] = {a0.x, a0.y, a0.z, a0.w, a1.x, a1.y, a1.z, a1.w};
            float b[4] = {b4.x, b4.y, b4.z, b4.w};
#pragma unroll
            for (int i = 0; i < 8; ++i)
#pragma unroll
                for (int j = 0; j < 4; ++j) acc[i][j] += a[i] * b[j];
        }
        __syncthreads();
    }
#pragma unroll
    for (int i = 0; i < 8; ++i) {
        int m = m0 + ty * 8 + i;
#pragma unroll
        for (int j = 0; j < 4; ++j) {
            int n = n0 + tx * 4 + j;
            out[(size_t)m * DIM_ + n] = acc[i][j];
        }
    }
}

extern "C" void kernel_launch(void* const* d_in, const int* in_sizes, int n_in,
                              void* d_out, int out_size, void* d_ws, size_t ws_size,
                              hipStream_t stream) {
    const float* x     = (const float*)d_in[0];
    const float* wqkv  = (const float*)d_in[1];
    const float* wgate = (const float*)d_in[2];
    const float* wout  = (const float*)d_in[3];
    float* out = (float*)d_out;

    float* ws = (float*)d_ws;
    float* qp = ws;                      // 2M floats
    float* kp = ws + 2 * 1024 * 1024;    // 2M
    float* vp = ws + 4 * 1024 * 1024;    // 2M
    float* gt = ws + 6 * 1024 * 1024;    // 2M (gate, then attention output in place)

    dim3 g1(NTOT_ / 64, M_ / 128);       // (64,16)
    gemm_in<<<g1, 256, 0, stream>>>(x, wqkv, wgate, qp, kp, vp, gt);

    dim3 g2(T_ / 64, H_, B_);            // (16,16,2)
    attn<<<g2, 64, 0, stream>>>(qp, kp, vp, gt);

    dim3 g3(DIM_ / 64, M_ / 128);        // (16,16)
    gemm_out<<<g3, 256, 0, stream>>>(gt, wout, out);
}

// Round 4
// 419.285 us; speedup vs baseline: 3.3639x; 3.3639x over previous
//
#include <hip/hip_runtime.h>
#include <hip/hip_bf16.h>
#include <math.h>

#define B_    2
#define T_    1024
#define DIM_  1024
#define H_    16
#define D_    64
#define M_    (B_ * T_)      // 2048 rows
#define NQKV_ 3072
#define NTOT_ 4096
#define NC_   16             // chunks of 64 along T

// elu(x)+1 == exp(x) for x<=0, x+1 for x>0
__device__ __forceinline__ float elu1(float x) {
    return x > 0.f ? x + 1.f : expf(x);
}

// ---------------------------------------------------------------------------
// Kernel A: fused input GEMM  x(2048,1024) @ [w_qkv(1024,3072) | w_gate(1024,1024)]
// epilogue applies elu+1 (q,k), sigmoid (gate), scatters to (B*T, H*D) bufs.
// ---------------------------------------------------------------------------
__global__ __launch_bounds__(256) void gemm_in(
    const float* __restrict__ x, const float* __restrict__ wqkv,
    const float* __restrict__ wgate, float* __restrict__ qp,
    float* __restrict__ kp, float* __restrict__ vp, float* __restrict__ gt) {
    __shared__ float As[16][128];
    __shared__ float Bs[16][64];
    const int tid = threadIdx.x;
    const int m0 = blockIdx.y * 128;
    const int n0 = blockIdx.x * 64;

    const float* wsrc;
    int wld, nc0;
    if (n0 < NQKV_) { wsrc = wqkv;  wld = NQKV_; nc0 = n0; }
    else            { wsrc = wgate; wld = DIM_;  nc0 = n0 - NQKV_; }

    const int tx = tid & 15;
    const int ty = tid >> 4;

    float acc[8][4];
#pragma unroll
    for (int i = 0; i < 8; ++i)
#pragma unroll
        for (int j = 0; j < 4; ++j) acc[i][j] = 0.f;

    const int ar = tid >> 2;
    const int ac = (tid & 3) * 4;
    const int br = tid >> 6;
    const int bc = tid & 63;

    for (int k0 = 0; k0 < DIM_; k0 += 16) {
#pragma unroll
        for (int rep = 0; rep < 2; ++rep) {
            float4 a = *(const float4*)&x[(size_t)(m0 + ar + rep * 64) * DIM_ + k0 + ac];
            As[ac + 0][ar + rep * 64] = a.x;
            As[ac + 1][ar + rep * 64] = a.y;
            As[ac + 2][ar + rep * 64] = a.z;
            As[ac + 3][ar + rep * 64] = a.w;
        }
#pragma unroll
        for (int rep = 0; rep < 4; ++rep) {
            Bs[br + rep * 4][bc] = wsrc[(size_t)(k0 + br + rep * 4) * wld + nc0 + bc];
        }
        __syncthreads();
#pragma unroll
        for (int kk = 0; kk < 16; ++kk) {
            float4 b4 = *(const float4*)&Bs[kk][tx * 4];
            float4 a0 = *(const float4*)&As[kk][ty * 8];
            float4 a1 = *(const float4*)&As[kk][ty * 8 + 4];
            float a[8] = {a0.x, a0.y, a0.z, a0.w, a1.x, a1.y, a1.z, a1.w};
            float b[4] = {b4.x, b4.y, b4.z, b4.w};
#pragma unroll
            for (int i = 0; i < 8; ++i)
#pragma unroll
                for (int j = 0; j < 4; ++j) acc[i][j] += a[i] * b[j];
        }
        __syncthreads();
    }

#pragma unroll
    for (int i = 0; i < 8; ++i) {
        int m = m0 + ty * 8 + i;
#pragma unroll
        for (int j = 0; j < 4; ++j) {
            int n = n0 + tx * 4 + j;
            float v = acc[i][j];
            if (n0 < NQKV_) {
                int s  = n >> 10;
                int hd = n & 1023;
                size_t o = (size_t)m * 1024 + hd;
                if (s == 0)      qp[o] = elu1(v);
                else if (s == 1) kp[o] = elu1(v);
                else             vp[o] = v;
            } else {
                gt[(size_t)m * 1024 + (n - NQKV_)] = 1.f / (1.f + expf(-v));
            }
        }
    }
}

// ---------------------------------------------------------------------------
// Kernel B1: per (b,h,chunk) local KV state  S_c[j][i] = sum_{s in c} k[j]*v[i]
// and ksum_c[j] = sum k[j].  256 threads; wave w owns i-range w*16..+15.
// ---------------------------------------------------------------------------
__global__ __launch_bounds__(256) void chunk_state(
    const float* __restrict__ kp, const float* __restrict__ vp,
    float* __restrict__ S, float* __restrict__ ksum) {
    __shared__ float kc[64][64];
    __shared__ float vc[64][64];
    const int tid = threadIdx.x;
    const int c = blockIdx.x, h = blockIdx.y, b = blockIdx.z;

#pragma unroll
    for (int rep = 0; rep < 4; ++rep) {
        int f = tid + rep * 256;          // float4 index 0..1023
        int r = f >> 4, c4 = (f & 15) * 4;
        size_t g = (size_t)(b * T_ + c * 64 + r) * 1024 + h * 64 + c4;
        *(float4*)&kc[r][c4] = *(const float4*)&kp[g];
        *(float4*)&vc[r][c4] = *(const float4*)&vp[g];
    }
    __syncthreads();

    const int j  = tid & 63;              // lane: k-dim index (stride-1 LDS)
    const int i0 = (tid >> 6) * 16;       // wave-uniform v-dim base (broadcast)
    float acc[16];
#pragma unroll
    for (int i = 0; i < 16; ++i) acc[i] = 0.f;

    for (int s = 0; s < 64; ++s) {
        float a = kc[s][j];
#pragma unroll
        for (int i4 = 0; i4 < 4; ++i4) {
            float4 v4 = *(const float4*)&vc[s][i0 + i4 * 4];
            acc[i4 * 4 + 0] += a * v4.x;
            acc[i4 * 4 + 1] += a * v4.y;
            acc[i4 * 4 + 2] += a * v4.z;
            acc[i4 * 4 + 3] += a * v4.w;
        }
    }
    size_t base = ((size_t)((b * H_ + h) * NC_ + c)) * 4096 + (size_t)j * 64 + i0;
#pragma unroll
    for (int i4 = 0; i4 < 4; ++i4) {
        float4 o = {acc[i4*4+0], acc[i4*4+1], acc[i4*4+2], acc[i4*4+3]};
        *(float4*)&S[base + i4 * 4] = o;
    }
    if (tid < 64) {
        float s = 0.f;
#pragma unroll 8
        for (int r = 0; r < 64; ++r) s += kc[r][tid];
        ksum[((size_t)((b * H_ + h) * NC_ + c)) * 64 + tid] = s;
    }
}

// ---------------------------------------------------------------------------
// Kernel B2: in-place EXCLUSIVE prefix over chunks for S and ksum, per (b,h).
// ---------------------------------------------------------------------------
__global__ __launch_bounds__(256) void prefix_state(
    float* __restrict__ S, float* __restrict__ ksum) {
    const int tid = threadIdx.x;
    const int h = blockIdx.x, b = blockIdx.y;
    size_t base = (size_t)(b * H_ + h) * NC_ * 4096 + (size_t)tid * 16;
    float acc[16];
#pragma unroll
    for (int i = 0; i < 16; ++i) acc[i] = 0.f;
    for (int c = 0; c < NC_; ++c) {
        size_t o = base + (size_t)c * 4096;
        float t[16];
#pragma unroll
        for (int i4 = 0; i4 < 4; ++i4) {
            float4 v = *(const float4*)&S[o + i4 * 4];
            t[i4*4+0] = v.x; t[i4*4+1] = v.y; t[i4*4+2] = v.z; t[i4*4+3] = v.w;
        }
#pragma unroll
        for (int i4 = 0; i4 < 4; ++i4) {
            float4 w = {acc[i4*4+0], acc[i4*4+1], acc[i4*4+2], acc[i4*4+3]};
            *(float4*)&S[o + i4 * 4] = w;
        }
#pragma unroll
        for (int i = 0; i < 16; ++i) acc[i] += t[i];
    }
    if (tid < 64) {
        size_t kb = (size_t)(b * H_ + h) * NC_ * 64 + tid;
        float a = 0.f;
        for (int c = 0; c < NC_; ++c) {
            float t = ksum[kb + (size_t)c * 64];
            ksum[kb + (size_t)c * 64] = a;
            a += t;
        }
    }
}

// ---------------------------------------------------------------------------
// Kernel B3: per (b,h,chunk) output.
// num_t = q_t @ P_c  +  sum_{s<=t in chunk} (q_t.k_s) v_s
// den_t = q_t . kpre_c + intra cumsum;  out = num/(den+1e-6)*gate (in place).
// One wave; lane = t within chunk. Hot-loop LDS reads are broadcast.
// ---------------------------------------------------------------------------
__global__ __launch_bounds__(64) void attn_out(
    const float* __restrict__ qp, const float* __restrict__ kp,
    const float* __restrict__ vp, const float* __restrict__ S,
    const float* __restrict__ ksum, float* __restrict__ gt_att) {
    __shared__ float P[64][64];       // prefix state (j,i)
    __shared__ float kc[64][68];
    __shared__ float vc[64][68];
    __shared__ float kpre[64];
    const int lane = threadIdx.x;
    const int c = blockIdx.x, h = blockIdx.y, b = blockIdx.z;
    const int t = c * 64 + lane;
    const size_t rowbase = (size_t)(b * T_ + t) * 1024 + h * 64;

    // stage q tile via LDS (coalesced), read own row to regs
    float q[64];
#pragma unroll 4
    for (int r = 0; r < 64; ++r) {
        vc[r][lane] = qp[(size_t)(b * T_ + c * 64 + r) * 1024 + h * 64 + lane];
    }
    __syncthreads();
#pragma unroll
    for (int d4 = 0; d4 < 16; ++d4) {
        float4 v = *(const float4*)&vc[lane][d4 * 4];
        q[d4*4+0] = v.x; q[d4*4+1] = v.y; q[d4*4+2] = v.z; q[d4*4+3] = v.w;
    }
    __syncthreads();

    // stage P, kc, vc, kpre
    const size_t sbase = ((size_t)((b * H_ + h) * NC_ + c)) * 4096;
#pragma unroll
    for (int rep = 0; rep < 16; ++rep) {
        int f = lane + rep * 64;          // float4 idx 0..1023
        int j = f >> 4, i4 = (f & 15) * 4;
        *(float4*)&P[j][i4] = *(const float4*)&S[sbase + (size_t)j * 64 + i4];
    }
    {
        const int cc = (lane & 15) * 4;
        const int r0 = lane >> 4;
#pragma unroll
        for (int rep = 0; rep < 16; ++rep) {
            int r = r0 + rep * 4;
            size_t g = (size_t)(b * T_ + c * 64 + r) * 1024 + h * 64 + cc;
            *(float4*)&kc[r][cc] = *(const float4*)&kp[g];
            *(float4*)&vc[r][cc] = *(const float4*)&vp[g];
        }
    }
    kpre[lane] = ksum[((size_t)((b * H_ + h) * NC_ + c)) * 64 + lane];
    __syncthreads();

    float num[64];
#pragma unroll
    for (int i = 0; i < 64; ++i) num[i] = 0.f;
    float den = 0.f;

    // intra-chunk causal part (LDS rows are wave-uniform -> broadcast)
    for (int r = 0; r <= lane; ++r) {
        float a = 0.f;
#pragma unroll
        for (int d4 = 0; d4 < 16; ++d4) {
            float4 kk = *(const float4*)&kc[r][d4 * 4];
            a += q[d4*4+0]*kk.x + q[d4*4+1]*kk.y + q[d4*4+2]*kk.z + q[d4*4+3]*kk.w;
        }
        den += a;
#pragma unroll
        for (int i4 = 0; i4 < 16; ++i4) {
            float4 vv = *(const float4*)&vc[r][i4 * 4];
            num[i4*4+0] += a * vv.x;
            num[i4*4+1] += a * vv.y;
            num[i4*4+2] += a * vv.z;
            num[i4*4+3] += a * vv.w;
        }
    }
    // inter-chunk: num += q @ P; den += q . kpre  (broadcast reads)
    for (int j = 0; j < 64; ++j) {
        float qj = q[j];
        den += qj * kpre[j];
#pragma unroll
        for (int i4 = 0; i4 < 16; ++i4) {
            float4 p4 = *(const float4*)&P[j][i4 * 4];
            num[i4*4+0] += qj * p4.x;
            num[i4*4+1] += qj * p4.y;
            num[i4*4+2] += qj * p4.z;
            num[i4*4+3] += qj * p4.w;
        }
    }

    const float inv = 1.f / (den + 1e-6f);
#pragma unroll
    for (int i4 = 0; i4 < 16; ++i4) {
        float4 g4 = *(const float4*)&gt_att[rowbase + i4 * 4];
        float4 o;
        o.x = num[i4*4+0] * inv * g4.x;
        o.y = num[i4*4+1] * inv * g4.y;
        o.z = num[i4*4+2] * inv * g4.z;
        o.w = num[i4*4+3] * inv * g4.w;
        *(float4*)&gt_att[rowbase + i4 * 4] = o;
    }
}

// ---------------------------------------------------------------------------
// Kernel C: output GEMM  att(2048,1024) @ w_out(1024,1024) -> out(2048,1024)
// ---------------------------------------------------------------------------
__global__ __launch_bounds__(256) void gemm_out(
    const float* __restrict__ att, const float* __restrict__ wout,
    float* __restrict__ out) {
    __shared__ float As[16][128];
    __shared__ float Bs[16][64];
    const int tid = threadIdx.x;
    const int m0 = blockIdx.y * 128;
    const int n0 = blockIdx.x * 64;
    const int tx = tid & 15;
    const int ty = tid >> 4;

    float acc[8][4];
#pragma unroll
    for (int i = 0; i < 8; ++i)
#pragma unroll
        for (int j = 0; j < 4; ++j) acc[i][j] = 0.f;

    const int ar = tid >> 2;
    const int ac = (tid & 3) * 4;
    const int br = tid >> 6;
    const int bc = tid & 63;

    for (int k0 = 0; k0 < DIM_; k0 += 16) {
#pragma unroll
        for (int rep = 0; rep < 2; ++rep) {
            float4 a = *(const float4*)&att[(size_t)(m0 + ar + rep * 64) * DIM_ + k0 + ac];
            As[ac + 0][ar + rep * 64] = a.x;
            As[ac + 1][ar + rep * 64] = a.y;
            As[ac + 2][ar + rep * 64] = a.z;
            As[ac + 3][ar + rep * 64] = a.w;
        }
#pragma unroll
        for (int rep = 0; rep < 4; ++rep) {
            Bs[br + rep * 4][bc] = wout[(size_t)(k0 + br + rep * 4) * DIM_ + n0 + bc];
        }
        __syncthreads();
#pragma unroll
        for (int kk = 0; kk < 16; ++kk) {
            float4 b4 = *(const float4*)&Bs[kk][tx * 4];
            float4 a0 = *(const float4*)&As[kk][ty * 8];
            float4 a1 = *(const float4*)&As[kk][ty * 8 + 4];
            float a[8] = {a0.x, a0.y, a0.z, a0.w, a1.x, a1.y, a1.z, a1.w};
            float b[4] = {b4.x, b4.y, b4.z, b4.w};
#pragma unroll
            for (int i = 0; i < 8; ++i)
#pragma unroll
                for (int j = 0; j < 4; ++j) acc[i][j] += a[i] * b[j];
        }
        __syncthreads();
    }
#pragma unroll
    for (int i = 0; i < 8; ++i) {
        int m = m0 + ty * 8 + i;
#pragma unroll
        for (int j = 0; j < 4; ++j) {
            int n = n0 + tx * 4 + j;
            out[(size_t)m * DIM_ + n] = acc[i][j];
        }
    }
}

extern "C" void kernel_launch(void* const* d_in, const int* in_sizes, int n_in,
                              void* d_out, int out_size, void* d_ws, size_t ws_size,
                              hipStream_t stream) {
    const float* x     = (const float*)d_in[0];
    const float* wqkv  = (const float*)d_in[1];
    const float* wgate = (const float*)d_in[2];
    const float* wout  = (const float*)d_in[3];
    float* out = (float*)d_out;

    float* ws = (float*)d_ws;
    float* qp   = ws;                       // 2M floats
    float* kp   = ws + 2 * 1024 * 1024;     // 2M
    float* vp   = ws + 4 * 1024 * 1024;     // 2M
    float* gt   = ws + 6 * 1024 * 1024;     // 2M (gate -> attn output in place)
    float* S    = ws + 8 * 1024 * 1024;     // 2M (B*H*NC*64*64)
    float* ksum = ws + 10 * 1024 * 1024;    // 32k (B*H*NC*64)

    dim3 g1(NTOT_ / 64, M_ / 128);          // (64,16)
    gemm_in<<<g1, 256, 0, stream>>>(x, wqkv, wgate, qp, kp, vp, gt);

    dim3 gs(NC_, H_, B_);                   // (16,16,2)
    chunk_state<<<gs, 256, 0, stream>>>(kp, vp, S, ksum);

    dim3 gp(H_, B_);                        // (16,2)
    prefix_state<<<gp, 256, 0, stream>>>(S, ksum);

    attn_out<<<gs, 64, 0, stream>>>(qp, kp, vp, S, ksum, gt);

    dim3 g3(DIM_ / 64, M_ / 128);           // (16,16)
    gemm_out<<<g3, 256, 0, stream>>>(gt, wout, out);
}

// Round 6
// 157.277 us; speedup vs baseline: 8.9678x; 2.6659x over previous
//
#include <hip/hip_runtime.h>
#include <hip/hip_bf16.h>
#include <math.h>

#define B_    2
#define T_    1024
#define DIM_  1024
#define H_    16
#define D_    64
#define M_    (B_ * T_)      // 2048 rows
#define NQKV_ 3072
#define NTOT_ 4096
#define NC_   16             // chunks of 64 along T

typedef __attribute__((ext_vector_type(8))) short short8v;   // 8 bf16
typedef __attribute__((ext_vector_type(4))) short short4v;   // 4 bf16
typedef __attribute__((ext_vector_type(4))) float floatx4;

__device__ __forceinline__ float elu1(float x) {
    return x > 0.f ? x + 1.f : expf(x);
}
__device__ __forceinline__ unsigned short f2bf(float f) {
    unsigned int u = __float_as_uint(f);
    unsigned int r = (u + 0x7FFFu + ((u >> 16) & 1u)) >> 16;   // RNE
    return (unsigned short)r;
}
// chunk-permutation for 64B-row LDS tiles: 2-way max bank aliasing (free)
__device__ __forceinline__ int swz(int r) { return (r & 3) ^ ((r >> 2) & 1); }

// ---------------------------------------------------------------------------
// pre-pass: cast x f32 -> bf16 (8 elems/thread)
// ---------------------------------------------------------------------------
__global__ __launch_bounds__(256) void cast_x(
    const float* __restrict__ src, __hip_bfloat16* __restrict__ dst) {
    int i = blockIdx.x * 256 + threadIdx.x;        // 8-elem group
    float4 v0 = ((const float4*)src)[i * 2];
    float4 v1 = ((const float4*)src)[i * 2 + 1];
    short8v o;
    o[0]=f2bf(v0.x); o[1]=f2bf(v0.y); o[2]=f2bf(v0.z); o[3]=f2bf(v0.w);
    o[4]=f2bf(v1.x); o[5]=f2bf(v1.y); o[6]=f2bf(v1.z); o[7]=f2bf(v1.w);
    *(short8v*)&dst[(size_t)i * 8] = o;
}

// ---------------------------------------------------------------------------
// pre-pass: transpose+cast weight (K=1024, srcN) f32 row-major -> bf16 [N][1024]
// ---------------------------------------------------------------------------
__global__ __launch_bounds__(256) void transw(
    const float* __restrict__ src, __hip_bfloat16* __restrict__ dst, int srcN) {
    __shared__ float t[32][33];
    const int n0 = blockIdx.x * 32, k0 = blockIdx.y * 32;
    const int tid = threadIdx.x;
    const int r  = tid >> 3;          // src row (k) within tile
    const int c4 = (tid & 7) * 4;     // src col group
    float4 v = *(const float4*)&src[(size_t)(k0 + r) * srcN + n0 + c4];
    t[c4 + 0][r] = v.x; t[c4 + 1][r] = v.y; t[c4 + 2][r] = v.z; t[c4 + 3][r] = v.w;
    __syncthreads();
    short4v o;
    o[0] = f2bf(t[tid >> 3][(tid & 7) * 4 + 0]);
    o[1] = f2bf(t[tid >> 3][(tid & 7) * 4 + 1]);
    o[2] = f2bf(t[tid >> 3][(tid & 7) * 4 + 2]);
    o[3] = f2bf(t[tid >> 3][(tid & 7) * 4 + 3]);
    *(short4v*)&dst[(size_t)(n0 + (tid >> 3)) * 1024 + k0 + (tid & 7) * 4] = o;
}

// ---------------------------------------------------------------------------
// MFMA GEMM core macro: 128x128 tile, BK=32, 4 waves, global_load_lds + swizzle.
// A: [M][1024] bf16 row-major; BT: [N][1024] bf16 row-major (B transposed).
// ---------------------------------------------------------------------------
#define GEMM_CORE(A_PTR, BT_PTR)                                               \
    __shared__ short As[128 * 32];                                             \
    __shared__ short Bs[128 * 32];                                             \
    const int tid  = threadIdx.x;                                              \
    const int lane = tid & 63;                                                 \
    const int w    = tid >> 6;                                                 \
    const int wr   = w >> 1, wc = w & 1;                                       \
    const int m0 = blockIdx.y * 128;                                           \
    const int n0 = blockIdx.x * 128;                                           \
    floatx4 acc[4][4];                                                         \
    _Pragma("unroll") for (int i = 0; i < 4; ++i)                              \
        _Pragma("unroll") for (int j = 0; j < 4; ++j)                          \
            acc[i][j] = (floatx4){0.f, 0.f, 0.f, 0.f};                         \
    for (int k0 = 0; k0 < 1024; k0 += 32) {                                    \
        _Pragma("unroll") for (int j = 0; j < 2; ++j) {                        \
            const int r = w * 32 + j * 16 + (lane >> 2);                       \
            const int c = (lane & 3) ^ swz(r);                                 \
            __builtin_amdgcn_global_load_lds(                                  \
                (const __attribute__((address_space(1))) unsigned int*)        \
                    (A_PTR + (size_t)(m0 + r) * 1024 + k0 + c * 8),            \
                (__attribute__((address_space(3))) unsigned int*)              \
                    (&As[(w * 32 + j * 16) * 32]), 16, 0, 0);                  \
            __builtin_amdgcn_global_load_lds(                                  \
                (const __attribute__((address_space(1))) unsigned int*)        \
                    (BT_PTR + (size_t)(n0 + r) * 1024 + k0 + c * 8),           \
                (__attribute__((address_space(3))) unsigned int*)              \
                    (&Bs[(w * 32 + j * 16) * 32]), 16, 0, 0);                  \
        }                                                                      \
        __syncthreads();                                                       \
        short8v af[4], bf[4];                                                  \
        _Pragma("unroll") for (int i = 0; i < 4; ++i) {                        \
            const int ra = wr * 64 + i * 16 + (lane & 15);                     \
            const int ca = (lane >> 4) ^ swz(ra);                              \
            af[i] = *(const short8v*)&As[ra * 32 + ca * 8];                    \
            const int rb = wc * 64 + i * 16 + (lane & 15);                     \
            const int cb = (lane >> 4) ^ swz(rb);                              \
            bf[i] = *(const short8v*)&Bs[rb * 32 + cb * 8];                    \
        }                                                                      \
        _Pragma("unroll") for (int i = 0; i < 4; ++i)                          \
            _Pragma("unroll") for (int j = 0; j < 4; ++j)                      \
                acc[i][j] = __builtin_amdgcn_mfma_f32_16x16x32_bf16(           \
                    af[i], bf[j], acc[i][j], 0, 0, 0);                         \
        __syncthreads();                                                       \
    }

// ---------------------------------------------------------------------------
// Kernel A: fused input GEMM (bf16 MFMA) with activation+scatter epilogue.
// ---------------------------------------------------------------------------
__global__ __launch_bounds__(256) void gemm_in_mfma(
    const __hip_bfloat16* __restrict__ xb, const __hip_bfloat16* __restrict__ wT,
    float* __restrict__ qp, float* __restrict__ kp,
    float* __restrict__ vp, float* __restrict__ gt) {
    GEMM_CORE(xb, wT)
    const int seg = n0 >> 10;                     // block-uniform: 0 q,1 k,2 v,3 gate
    float* dst = (seg == 0) ? qp : (seg == 1) ? kp : (seg == 2) ? vp : gt;
    const int colbase = (n0 & 1023) + wc * 64 + (lane & 15);
#pragma unroll
    for (int i = 0; i < 4; ++i) {
        const int rowb = m0 + wr * 64 + i * 16 + (lane >> 4) * 4;
#pragma unroll
        for (int j = 0; j < 4; ++j) {
            const int col = colbase + j * 16;
#pragma unroll
            for (int r2 = 0; r2 < 4; ++r2) {
                float v = acc[i][j][r2];
                float o;
                if (seg <= 1)      o = elu1(v);
                else if (seg == 2) o = v;
                else               o = 1.f / (1.f + expf(-v));
                dst[(size_t)(rowb + r2) * 1024 + col] = o;
            }
        }
    }
}

// ---------------------------------------------------------------------------
// Kernel C: output GEMM (bf16 MFMA), plain f32 store.
// ---------------------------------------------------------------------------
__global__ __launch_bounds__(256) void gemm_out_mfma(
    const __hip_bfloat16* __restrict__ ab, const __hip_bfloat16* __restrict__ wT,
    float* __restrict__ out) {
    GEMM_CORE(ab, wT)
    const int colbase = n0 + wc * 64 + (lane & 15);
#pragma unroll
    for (int i = 0; i < 4; ++i) {
        const int rowb = m0 + wr * 64 + i * 16 + (lane >> 4) * 4;
#pragma unroll
        for (int j = 0; j < 4; ++j) {
#pragma unroll
            for (int r2 = 0; r2 < 4; ++r2)
                out[(size_t)(rowb + r2) * 1024 + colbase + j * 16] = acc[i][j][r2];
        }
    }
}

// ---------------------------------------------------------------------------
// Kernel B1: per (b,h,chunk) local KV state (f32, unchanged)
// ---------------------------------------------------------------------------
__global__ __launch_bounds__(256) void chunk_state(
    const float* __restrict__ kp, const float* __restrict__ vp,
    float* __restrict__ S, float* __restrict__ ksum) {
    __shared__ float kc[64][64];
    __shared__ float vc[64][64];
    const int tid = threadIdx.x;
    const int c = blockIdx.x, h = blockIdx.y, b = blockIdx.z;
#pragma unroll
    for (int rep = 0; rep < 4; ++rep) {
        int f = tid + rep * 256;
        int r = f >> 4, c4 = (f & 15) * 4;
        size_t g = (size_t)(b * T_ + c * 64 + r) * 1024 + h * 64 + c4;
        *(float4*)&kc[r][c4] = *(const float4*)&kp[g];
        *(float4*)&vc[r][c4] = *(const float4*)&vp[g];
    }
    __syncthreads();
    const int j  = tid & 63;
    const int i0 = (tid >> 6) * 16;
    float acc[16];
#pragma unroll
    for (int i = 0; i < 16; ++i) acc[i] = 0.f;
    for (int s = 0; s < 64; ++s) {
        float a = kc[s][j];
#pragma unroll
        for (int i4 = 0; i4 < 4; ++i4) {
            float4 v4 = *(const float4*)&vc[s][i0 + i4 * 4];
            acc[i4*4+0] += a * v4.x; acc[i4*4+1] += a * v4.y;
            acc[i4*4+2] += a * v4.z; acc[i4*4+3] += a * v4.w;
        }
    }
    size_t base = ((size_t)((b * H_ + h) * NC_ + c)) * 4096 + (size_t)j * 64 + i0;
#pragma unroll
    for (int i4 = 0; i4 < 4; ++i4) {
        float4 o = {acc[i4*4+0], acc[i4*4+1], acc[i4*4+2], acc[i4*4+3]};
        *(float4*)&S[base + i4 * 4] = o;
    }
    if (tid < 64) {
        float s = 0.f;
#pragma unroll 8
        for (int r = 0; r < 64; ++r) s += kc[r][tid];
        ksum[((size_t)((b * H_ + h) * NC_ + c)) * 64 + tid] = s;
    }
}

// ---------------------------------------------------------------------------
// Kernel B2: exclusive prefix over chunks (unchanged)
// ---------------------------------------------------------------------------
__global__ __launch_bounds__(256) void prefix_state(
    float* __restrict__ S, float* __restrict__ ksum) {
    const int tid = threadIdx.x;
    const int h = blockIdx.x, b = blockIdx.y;
    size_t base = (size_t)(b * H_ + h) * NC_ * 4096 + (size_t)tid * 16;
    float acc[16];
#pragma unroll
    for (int i = 0; i < 16; ++i) acc[i] = 0.f;
    for (int c = 0; c < NC_; ++c) {
        size_t o = base + (size_t)c * 4096;
        float t[16];
#pragma unroll
        for (int i4 = 0; i4 < 4; ++i4) {
            float4 v = *(const float4*)&S[o + i4 * 4];
            t[i4*4+0]=v.x; t[i4*4+1]=v.y; t[i4*4+2]=v.z; t[i4*4+3]=v.w;
        }
#pragma unroll
        for (int i4 = 0; i4 < 4; ++i4) {
            float4 w = {acc[i4*4+0], acc[i4*4+1], acc[i4*4+2], acc[i4*4+3]};
            *(float4*)&S[o + i4 * 4] = w;
        }
#pragma unroll
        for (int i = 0; i < 16; ++i) acc[i] += t[i];
    }
    if (tid < 64) {
        size_t kb = (size_t)(b * H_ + h) * NC_ * 64 + tid;
        float a = 0.f;
        for (int c = 0; c < NC_; ++c) {
            float t = ksum[kb + (size_t)c * 64];
            ksum[kb + (size_t)c * 64] = a;
            a += t;
        }
    }
}

// ---------------------------------------------------------------------------
// Kernel B3: per (b,h,chunk) output; now emits bf16 att for gemm_out.
// ---------------------------------------------------------------------------
__global__ __launch_bounds__(64) void attn_out(
    const float* __restrict__ qp, const float* __restrict__ kp,
    const float* __restrict__ vp, const float* __restrict__ S,
    const float* __restrict__ ksum, const float* __restrict__ gt,
    __hip_bfloat16* __restrict__ att_b) {
    __shared__ float P[64][64];
    __shared__ float kc[64][68];
    __shared__ float vc[64][68];
    __shared__ float kpre[64];
    const int lane = threadIdx.x;
    const int c = blockIdx.x, h = blockIdx.y, b = blockIdx.z;
    const int t = c * 64 + lane;
    const size_t rowbase = (size_t)(b * T_ + t) * 1024 + h * 64;

    float q[64];
#pragma unroll 4
    for (int r = 0; r < 64; ++r) {
        vc[r][lane] = qp[(size_t)(b * T_ + c * 64 + r) * 1024 + h * 64 + lane];
    }
    __syncthreads();
#pragma unroll
    for (int d4 = 0; d4 < 16; ++d4) {
        float4 v = *(const float4*)&vc[lane][d4 * 4];
        q[d4*4+0]=v.x; q[d4*4+1]=v.y; q[d4*4+2]=v.z; q[d4*4+3]=v.w;
    }
    __syncthreads();

    const size_t sbase = ((size_t)((b * H_ + h) * NC_ + c)) * 4096;
#pragma unroll
    for (int rep = 0; rep < 16; ++rep) {
        int f = lane + rep * 64;
        int j = f >> 4, i4 = (f & 15) * 4;
        *(float4*)&P[j][i4] = *(const float4*)&S[sbase + (size_t)j * 64 + i4];
    }
    {
        const int cc = (lane & 15) * 4;
        const int r0 = lane >> 4;
#pragma unroll
        for (int rep = 0; rep < 16; ++rep) {
            int r = r0 + rep * 4;
            size_t g = (size_t)(b * T_ + c * 64 + r) * 1024 + h * 64 + cc;
            *(float4*)&kc[r][cc] = *(const float4*)&kp[g];
            *(float4*)&vc[r][cc] = *(const float4*)&vp[g];
        }
    }
    kpre[lane] = ksum[((size_t)((b * H_ + h) * NC_ + c)) * 64 + lane];
    __syncthreads();

    float num[64];
#pragma unroll
    for (int i = 0; i < 64; ++i) num[i] = 0.f;
    float den = 0.f;

    for (int r = 0; r <= lane; ++r) {
        float a = 0.f;
#pragma unroll
        for (int d4 = 0; d4 < 16; ++d4) {
            float4 kk = *(const float4*)&kc[r][d4 * 4];
            a += q[d4*4+0]*kk.x + q[d4*4+1]*kk.y + q[d4*4+2]*kk.z + q[d4*4+3]*kk.w;
        }
        den += a;
#pragma unroll
        for (int i4 = 0; i4 < 16; ++i4) {
            float4 vv = *(const float4*)&vc[r][i4 * 4];
            num[i4*4+0] += a * vv.x; num[i4*4+1] += a * vv.y;
            num[i4*4+2] += a * vv.z; num[i4*4+3] += a * vv.w;
        }
    }
    for (int j = 0; j < 64; ++j) {
        float qj = q[j];
        den += qj * kpre[j];
#pragma unroll
        for (int i4 = 0; i4 < 16; ++i4) {
            float4 p4 = *(const float4*)&P[j][i4 * 4];
            num[i4*4+0] += qj * p4.x; num[i4*4+1] += qj * p4.y;
            num[i4*4+2] += qj * p4.z; num[i4*4+3] += qj * p4.w;
        }
    }

    const float inv = 1.f / (den + 1e-6f);
#pragma unroll
    for (int i8 = 0; i8 < 8; ++i8) {
        float4 g0 = *(const float4*)&gt[rowbase + i8 * 8];
        float4 g1 = *(const float4*)&gt[rowbase + i8 * 8 + 4];
        short8v o;
        o[0] = (short)f2bf(num[i8*8+0] * inv * g0.x);
        o[1] = (short)f2bf(num[i8*8+1] * inv * g0.y);
        o[2] = (short)f2bf(num[i8*8+2] * inv * g0.z);
        o[3] = (short)f2bf(num[i8*8+3] * inv * g0.w);
        o[4] = (short)f2bf(num[i8*8+4] * inv * g1.x);
        o[5] = (short)f2bf(num[i8*8+5] * inv * g1.y);
        o[6] = (short)f2bf(num[i8*8+6] * inv * g1.z);
        o[7] = (short)f2bf(num[i8*8+7] * inv * g1.w);
        *(short8v*)&att_b[rowbase + i8 * 8] = o;
    }
}

extern "C" void kernel_launch(void* const* d_in, const int* in_sizes, int n_in,
                              void* d_out, int out_size, void* d_ws, size_t ws_size,
                              hipStream_t stream) {
    const float* x     = (const float*)d_in[0];
    const float* wqkv  = (const float*)d_in[1];
    const float* wgate = (const float*)d_in[2];
    const float* wout  = (const float*)d_in[3];
    float* out = (float*)d_out;

    char* ws = (char*)d_ws;
    float* qp   = (float*)(ws + 0);                    // 8 MB
    float* kp   = (float*)(ws + (8u << 20));           // 8 MB
    float* vp   = (float*)(ws + (16u << 20));          // 8 MB
    float* gt   = (float*)(ws + (24u << 20));          // 8 MB
    float* S    = (float*)(ws + (32u << 20));          // 8 MB
    float* ksum = (float*)(ws + (40u << 20));          // 128 KB
    __hip_bfloat16* xb    = (__hip_bfloat16*)(ws + (41u << 20));  // 4 MB
    __hip_bfloat16* wT    = (__hip_bfloat16*)(ws + (45u << 20));  // 8 MB [4096][1024]
    __hip_bfloat16* woutT = (__hip_bfloat16*)(ws + (53u << 20));  // 2 MB
    __hip_bfloat16* att_b = (__hip_bfloat16*)(ws + (55u << 20));  // 4 MB

    // pre-pass: casts / transposes
    cast_x<<<M_ * DIM_ / 8 / 256, 256, 0, stream>>>(x, xb);
    transw<<<dim3(NQKV_ / 32, DIM_ / 32), 256, 0, stream>>>(wqkv, wT, NQKV_);
    transw<<<dim3(DIM_ / 32, DIM_ / 32), 256, 0, stream>>>(wgate, wT + (size_t)NQKV_ * 1024, DIM_);
    transw<<<dim3(DIM_ / 32, DIM_ / 32), 256, 0, stream>>>(wout, woutT, DIM_);

    dim3 g1(NTOT_ / 128, M_ / 128);         // (32,16)
    gemm_in_mfma<<<g1, 256, 0, stream>>>(xb, wT, qp, kp, vp, gt);

    dim3 gs(NC_, H_, B_);                   // (16,16,2)
    chunk_state<<<gs, 256, 0, stream>>>(kp, vp, S, ksum);

    dim3 gp(H_, B_);                        // (16,2)
    prefix_state<<<gp, 256, 0, stream>>>(S, ksum);

    attn_out<<<gs, 64, 0, stream>>>(qp, kp, vp, S, ksum, gt, att_b);

    dim3 g3(DIM_ / 128, M_ / 128);          // (8,16)
    gemm_out_mfma<<<g3, 256, 0, stream>>>(att_b, woutT, out);
}

// Round 7
// 148.277 us; speedup vs baseline: 9.5121x; 1.0607x over previous
//
#include <hip/hip_runtime.h>
#include <hip/hip_bf16.h>
#include <math.h>

#define B_    2
#define T_    1024
#define DIM_  1024
#define H_    16
#define D_    64
#define M_    (B_ * T_)      // 2048 rows
#define NQKV_ 3072
#define NTOT_ 4096
#define NC_   16             // chunks of 64 along T

typedef __attribute__((ext_vector_type(8))) short short8v;   // 8 bf16
typedef __attribute__((ext_vector_type(4))) short short4v;   // 4 bf16
typedef __attribute__((ext_vector_type(4))) float floatx4;

__device__ __forceinline__ float elu1(float x) {
    return x > 0.f ? x + 1.f : expf(x);
}
__device__ __forceinline__ unsigned short f2bf(float f) {
    unsigned int u = __float_as_uint(f);
    unsigned int r = (u + 0x7FFFu + ((u >> 16) & 1u)) >> 16;   // RNE
    return (unsigned short)r;
}
// chunk-permutation for 64B-row LDS tiles: 2-way max bank aliasing (free)
__device__ __forceinline__ int swz(int r) { return (r & 3) ^ ((r >> 2) & 1); }

// ---------------------------------------------------------------------------
// pre-pass: cast x f32 -> bf16 (8 elems/thread)
// ---------------------------------------------------------------------------
__global__ __launch_bounds__(256) void cast_x(
    const float* __restrict__ src, __hip_bfloat16* __restrict__ dst) {
    int i = blockIdx.x * 256 + threadIdx.x;        // 8-elem group
    float4 v0 = ((const float4*)src)[i * 2];
    float4 v1 = ((const float4*)src)[i * 2 + 1];
    short8v o;
    o[0]=f2bf(v0.x); o[1]=f2bf(v0.y); o[2]=f2bf(v0.z); o[3]=f2bf(v0.w);
    o[4]=f2bf(v1.x); o[5]=f2bf(v1.y); o[6]=f2bf(v1.z); o[7]=f2bf(v1.w);
    *(short8v*)&dst[(size_t)i * 8] = o;
}

// ---------------------------------------------------------------------------
// pre-pass: transpose+cast weight (K=1024, srcN) f32 row-major -> bf16 [N][1024]
// ---------------------------------------------------------------------------
__global__ __launch_bounds__(256) void transw(
    const float* __restrict__ src, __hip_bfloat16* __restrict__ dst, int srcN) {
    __shared__ float t[32][33];
    const int n0 = blockIdx.x * 32, k0 = blockIdx.y * 32;
    const int tid = threadIdx.x;
    const int r  = tid >> 3;          // src row (k) within tile
    const int c4 = (tid & 7) * 4;     // src col group
    float4 v = *(const float4*)&src[(size_t)(k0 + r) * srcN + n0 + c4];
    t[c4 + 0][r] = v.x; t[c4 + 1][r] = v.y; t[c4 + 2][r] = v.z; t[c4 + 3][r] = v.w;
    __syncthreads();
    short4v o;
    o[0] = f2bf(t[tid >> 3][(tid & 7) * 4 + 0]);
    o[1] = f2bf(t[tid >> 3][(tid & 7) * 4 + 1]);
    o[2] = f2bf(t[tid >> 3][(tid & 7) * 4 + 2]);
    o[3] = f2bf(t[tid >> 3][(tid & 7) * 4 + 3]);
    *(short4v*)&dst[(size_t)(n0 + (tid >> 3)) * 1024 + k0 + (tid & 7) * 4] = o;
}

// ---------------------------------------------------------------------------
// MFMA GEMM core macro: 128x128 tile, BK=32, 4 waves, global_load_lds + swizzle.
// A: [M][1024] bf16 row-major; BT: [N][1024] bf16 row-major (B transposed).
// ---------------------------------------------------------------------------
#define GEMM_CORE(A_PTR, BT_PTR)                                               \
    __shared__ short As[128 * 32];                                             \
    __shared__ short Bs[128 * 32];                                             \
    const int tid  = threadIdx.x;                                              \
    const int lane = tid & 63;                                                 \
    const int w    = tid >> 6;                                                 \
    const int wr   = w >> 1, wc = w & 1;                                       \
    const int m0 = blockIdx.y * 128;                                           \
    const int n0 = blockIdx.x * 128;                                           \
    floatx4 acc[4][4];                                                         \
    _Pragma("unroll") for (int i = 0; i < 4; ++i)                              \
        _Pragma("unroll") for (int j = 0; j < 4; ++j)                          \
            acc[i][j] = (floatx4){0.f, 0.f, 0.f, 0.f};                         \
    for (int k0 = 0; k0 < 1024; k0 += 32) {                                    \
        _Pragma("unroll") for (int j = 0; j < 2; ++j) {                        \
            const int r = w * 32 + j * 16 + (lane >> 2);                       \
            const int c = (lane & 3) ^ swz(r);                                 \
            __builtin_amdgcn_global_load_lds(                                  \
                (const __attribute__((address_space(1))) unsigned int*)        \
                    (A_PTR + (size_t)(m0 + r) * 1024 + k0 + c * 8),            \
                (__attribute__((address_space(3))) unsigned int*)              \
                    (&As[(w * 32 + j * 16) * 32]), 16, 0, 0);                  \
            __builtin_amdgcn_global_load_lds(                                  \
                (const __attribute__((address_space(1))) unsigned int*)        \
                    (BT_PTR + (size_t)(n0 + r) * 1024 + k0 + c * 8),           \
                (__attribute__((address_space(3))) unsigned int*)              \
                    (&Bs[(w * 32 + j * 16) * 32]), 16, 0, 0);                  \
        }                                                                      \
        __syncthreads();                                                       \
        short8v af[4], bf[4];                                                  \
        _Pragma("unroll") for (int i = 0; i < 4; ++i) {                        \
            const int ra = wr * 64 + i * 16 + (lane & 15);                     \
            const int ca = (lane >> 4) ^ swz(ra);                              \
            af[i] = *(const short8v*)&As[ra * 32 + ca * 8];                    \
            const int rb = wc * 64 + i * 16 + (lane & 15);                     \
            const int cb = (lane >> 4) ^ swz(rb);                              \
            bf[i] = *(const short8v*)&Bs[rb * 32 + cb * 8];                    \
        }                                                                      \
        _Pragma("unroll") for (int i = 0; i < 4; ++i)                          \
            _Pragma("unroll") for (int j = 0; j < 4; ++j)                      \
                acc[i][j] = __builtin_amdgcn_mfma_f32_16x16x32_bf16(           \
                    af[i], bf[j], acc[i][j], 0, 0, 0);                         \
        __syncthreads();                                                       \
    }

// ---------------------------------------------------------------------------
// Kernel A: fused input GEMM (bf16 MFMA) with activation+scatter epilogue.
// ---------------------------------------------------------------------------
__global__ __launch_bounds__(256) void gemm_in_mfma(
    const __hip_bfloat16* __restrict__ xb, const __hip_bfloat16* __restrict__ wT,
    float* __restrict__ qp, float* __restrict__ kp,
    float* __restrict__ vp, float* __restrict__ gt) {
    GEMM_CORE(xb, wT)
    const int seg = n0 >> 10;                     // block-uniform: 0 q,1 k,2 v,3 gate
    float* dst = (seg == 0) ? qp : (seg == 1) ? kp : (seg == 2) ? vp : gt;
    const int colbase = (n0 & 1023) + wc * 64 + (lane & 15);
#pragma unroll
    for (int i = 0; i < 4; ++i) {
        const int rowb = m0 + wr * 64 + i * 16 + (lane >> 4) * 4;
#pragma unroll
        for (int j = 0; j < 4; ++j) {
            const int col = colbase + j * 16;
#pragma unroll
            for (int r2 = 0; r2 < 4; ++r2) {
                float v = acc[i][j][r2];
                float o;
                if (seg <= 1)      o = elu1(v);
                else if (seg == 2) o = v;
                else               o = 1.f / (1.f + expf(-v));
                dst[(size_t)(rowb + r2) * 1024 + col] = o;
            }
        }
    }
}

// ---------------------------------------------------------------------------
// Kernel C: output GEMM (bf16 MFMA), plain f32 store.
// ---------------------------------------------------------------------------
__global__ __launch_bounds__(256) void gemm_out_mfma(
    const __hip_bfloat16* __restrict__ ab, const __hip_bfloat16* __restrict__ wT,
    float* __restrict__ out) {
    GEMM_CORE(ab, wT)
    const int colbase = n0 + wc * 64 + (lane & 15);
#pragma unroll
    for (int i = 0; i < 4; ++i) {
        const int rowb = m0 + wr * 64 + i * 16 + (lane >> 4) * 4;
#pragma unroll
        for (int j = 0; j < 4; ++j) {
#pragma unroll
            for (int r2 = 0; r2 < 4; ++r2)
                out[(size_t)(rowb + r2) * 1024 + colbase + j * 16] = acc[i][j][r2];
        }
    }
}

// ---------------------------------------------------------------------------
// Kernel B1: per (b,h,chunk) local KV state (f32, unchanged)
// ---------------------------------------------------------------------------
__global__ __launch_bounds__(256) void chunk_state(
    const float* __restrict__ kp, const float* __restrict__ vp,
    float* __restrict__ S, float* __restrict__ ksum) {
    __shared__ float kc[64][64];
    __shared__ float vc[64][64];
    const int tid = threadIdx.x;
    const int c = blockIdx.x, h = blockIdx.y, b = blockIdx.z;
#pragma unroll
    for (int rep = 0; rep < 4; ++rep) {
        int f = tid + rep * 256;
        int r = f >> 4, c4 = (f & 15) * 4;
        size_t g = (size_t)(b * T_ + c * 64 + r) * 1024 + h * 64 + c4;
        *(float4*)&kc[r][c4] = *(const float4*)&kp[g];
        *(float4*)&vc[r][c4] = *(const float4*)&vp[g];
    }
    __syncthreads();
    const int j  = tid & 63;
    const int i0 = (tid >> 6) * 16;
    float acc[16];
#pragma unroll
    for (int i = 0; i < 16; ++i) acc[i] = 0.f;
    for (int s = 0; s < 64; ++s) {
        float a = kc[s][j];
#pragma unroll
        for (int i4 = 0; i4 < 4; ++i4) {
            float4 v4 = *(const float4*)&vc[s][i0 + i4 * 4];
            acc[i4*4+0] += a * v4.x; acc[i4*4+1] += a * v4.y;
            acc[i4*4+2] += a * v4.z; acc[i4*4+3] += a * v4.w;
        }
    }
    size_t base = ((size_t)((b * H_ + h) * NC_ + c)) * 4096 + (size_t)j * 64 + i0;
#pragma unroll
    for (int i4 = 0; i4 < 4; ++i4) {
        float4 o = {acc[i4*4+0], acc[i4*4+1], acc[i4*4+2], acc[i4*4+3]};
        *(float4*)&S[base + i4 * 4] = o;
    }
    if (tid < 64) {
        float s = 0.f;
#pragma unroll 8
        for (int r = 0; r < 64; ++r) s += kc[r][tid];
        ksum[((size_t)((b * H_ + h) * NC_ + c)) * 64 + tid] = s;
    }
}

// ---------------------------------------------------------------------------
// Kernel B2: exclusive prefix over chunks (unchanged)
// ---------------------------------------------------------------------------
__global__ __launch_bounds__(256) void prefix_state(
    float* __restrict__ S, float* __restrict__ ksum) {
    const int tid = threadIdx.x;
    const int h = blockIdx.x, b = blockIdx.y;
    size_t base = (size_t)(b * H_ + h) * NC_ * 4096 + (size_t)tid * 16;
    float acc[16];
#pragma unroll
    for (int i = 0; i < 16; ++i) acc[i] = 0.f;
    for (int c = 0; c < NC_; ++c) {
        size_t o = base + (size_t)c * 4096;
        float t[16];
#pragma unroll
        for (int i4 = 0; i4 < 4; ++i4) {
            float4 v = *(const float4*)&S[o + i4 * 4];
            t[i4*4+0]=v.x; t[i4*4+1]=v.y; t[i4*4+2]=v.z; t[i4*4+3]=v.w;
        }
#pragma unroll
        for (int i4 = 0; i4 < 4; ++i4) {
            float4 w = {acc[i4*4+0], acc[i4*4+1], acc[i4*4+2], acc[i4*4+3]};
            *(float4*)&S[o + i4 * 4] = w;
        }
#pragma unroll
        for (int i = 0; i < 16; ++i) acc[i] += t[i];
    }
    if (tid < 64) {
        size_t kb = (size_t)(b * H_ + h) * NC_ * 64 + tid;
        float a = 0.f;
        for (int c = 0; c < NC_; ++c) {
            float t = ksum[kb + (size_t)c * 64];
            ksum[kb + (size_t)c * 64] = a;
            a += t;
        }
    }
}

// ---------------------------------------------------------------------------
// Kernel B3: per (b,h,chunk) output, 4 waves.  Wave w owns out-cols
// [w*16, w*16+16); lane owns row t.  Scores and den recomputed per wave
// (broadcast LDS reads); num accumulators shrink 64 -> 16 per lane.
// ---------------------------------------------------------------------------
__global__ __launch_bounds__(256) void attn_out(
    const float* __restrict__ qp, const float* __restrict__ kp,
    const float* __restrict__ vp, const float* __restrict__ S,
    const float* __restrict__ ksum, const float* __restrict__ gt,
    __hip_bfloat16* __restrict__ att_b) {
    __shared__ float P[64][64];
    __shared__ float kc[64][68];
    __shared__ float vc[64][68];
    __shared__ float kpre[64];
    const int tid  = threadIdx.x;
    const int lane = tid & 63;
    const int w    = tid >> 6;
    const int i0   = w * 16;
    const int c = blockIdx.x, h = blockIdx.y, b = blockIdx.z;
    const int t = c * 64 + lane;
    const size_t rowbase = (size_t)(b * T_ + t) * 1024 + h * 64;

    // stage q tile via vc (coalesced), each lane reads its own row
#pragma unroll
    for (int rep = 0; rep < 4; ++rep) {
        int f = tid + rep * 256;
        int r = f >> 4, c4 = (f & 15) * 4;
        *(float4*)&vc[r][c4] =
            *(const float4*)&qp[(size_t)(b * T_ + c * 64 + r) * 1024 + h * 64 + c4];
    }
    __syncthreads();
    float q[64];
#pragma unroll
    for (int d4 = 0; d4 < 16; ++d4) {
        float4 v = *(const float4*)&vc[lane][d4 * 4];
        q[d4*4+0]=v.x; q[d4*4+1]=v.y; q[d4*4+2]=v.z; q[d4*4+3]=v.w;
    }
    __syncthreads();

    // stage P, kc, vc, kpre (256 threads)
    const size_t sbase = ((size_t)((b * H_ + h) * NC_ + c)) * 4096;
#pragma unroll
    for (int rep = 0; rep < 4; ++rep) {
        int f = tid + rep * 256;
        int j = f >> 4, i4 = (f & 15) * 4;
        *(float4*)&P[j][i4] = *(const float4*)&S[sbase + (size_t)j * 64 + i4];
    }
#pragma unroll
    for (int rep = 0; rep < 4; ++rep) {
        int f = tid + rep * 256;
        int r = f >> 4, c4 = (f & 15) * 4;
        size_t g = (size_t)(b * T_ + c * 64 + r) * 1024 + h * 64 + c4;
        *(float4*)&kc[r][c4] = *(const float4*)&kp[g];
        *(float4*)&vc[r][c4] = *(const float4*)&vp[g];
    }
    if (tid < 64) kpre[tid] = ksum[((size_t)((b * H_ + h) * NC_ + c)) * 64 + tid];
    __syncthreads();

    float num[16];
#pragma unroll
    for (int i = 0; i < 16; ++i) num[i] = 0.f;
    float den = 0.f;

    // intra-chunk causal part: score a recomputed per wave (broadcast reads)
    for (int r = 0; r <= lane; ++r) {
        float a = 0.f;
#pragma unroll
        for (int d4 = 0; d4 < 16; ++d4) {
            float4 kk = *(const float4*)&kc[r][d4 * 4];
            a += q[d4*4+0]*kk.x + q[d4*4+1]*kk.y + q[d4*4+2]*kk.z + q[d4*4+3]*kk.w;
        }
        den += a;
#pragma unroll
        for (int i4 = 0; i4 < 4; ++i4) {
            float4 vv = *(const float4*)&vc[r][i0 + i4 * 4];
            num[i4*4+0] += a * vv.x; num[i4*4+1] += a * vv.y;
            num[i4*4+2] += a * vv.z; num[i4*4+3] += a * vv.w;
        }
    }
    // inter-chunk: num += q @ P[:, i0:i0+16]; den += q . kpre
    for (int j = 0; j < 64; ++j) {
        float qj = q[j];
        den += qj * kpre[j];
#pragma unroll
        for (int i4 = 0; i4 < 4; ++i4) {
            float4 p4 = *(const float4*)&P[j][i0 + i4 * 4];
            num[i4*4+0] += qj * p4.x; num[i4*4+1] += qj * p4.y;
            num[i4*4+2] += qj * p4.z; num[i4*4+3] += qj * p4.w;
        }
    }

    const float inv = 1.f / (den + 1e-6f);
#pragma unroll
    for (int i8 = 0; i8 < 2; ++i8) {
        float4 g0 = *(const float4*)&gt[rowbase + i0 + i8 * 8];
        float4 g1 = *(const float4*)&gt[rowbase + i0 + i8 * 8 + 4];
        short8v o;
        o[0] = (short)f2bf(num[i8*8+0] * inv * g0.x);
        o[1] = (short)f2bf(num[i8*8+1] * inv * g0.y);
        o[2] = (short)f2bf(num[i8*8+2] * inv * g0.z);
        o[3] = (short)f2bf(num[i8*8+3] * inv * g0.w);
        o[4] = (short)f2bf(num[i8*8+4] * inv * g1.x);
        o[5] = (short)f2bf(num[i8*8+5] * inv * g1.y);
        o[6] = (short)f2bf(num[i8*8+6] * inv * g1.z);
        o[7] = (short)f2bf(num[i8*8+7] * inv * g1.w);
        *(short8v*)&att_b[rowbase + i0 + i8 * 8] = o;
    }
}

extern "C" void kernel_launch(void* const* d_in, const int* in_sizes, int n_in,
                              void* d_out, int out_size, void* d_ws, size_t ws_size,
                              hipStream_t stream) {
    const float* x     = (const float*)d_in[0];
    const float* wqkv  = (const float*)d_in[1];
    const float* wgate = (const float*)d_in[2];
    const float* wout  = (const float*)d_in[3];
    float* out = (float*)d_out;

    char* ws = (char*)d_ws;
    float* qp   = (float*)(ws + 0);                    // 8 MB
    float* kp   = (float*)(ws + (8u << 20));           // 8 MB
    float* vp   = (float*)(ws + (16u << 20));          // 8 MB
    float* gt   = (float*)(ws + (24u << 20));          // 8 MB
    float* S    = (float*)(ws + (32u << 20));          // 8 MB
    float* ksum = (float*)(ws + (40u << 20));          // 128 KB
    __hip_bfloat16* xb    = (__hip_bfloat16*)(ws + (41u << 20));  // 4 MB
    __hip_bfloat16* wT    = (__hip_bfloat16*)(ws + (45u << 20));  // 8 MB [4096][1024]
    __hip_bfloat16* woutT = (__hip_bfloat16*)(ws + (53u << 20));  // 2 MB
    __hip_bfloat16* att_b = (__hip_bfloat16*)(ws + (55u << 20));  // 4 MB

    // pre-pass: casts / transposes
    cast_x<<<M_ * DIM_ / 8 / 256, 256, 0, stream>>>(x, xb);
    transw<<<dim3(NQKV_ / 32, DIM_ / 32), 256, 0, stream>>>(wqkv, wT, NQKV_);
    transw<<<dim3(DIM_ / 32, DIM_ / 32), 256, 0, stream>>>(wgate, wT + (size_t)NQKV_ * 1024, DIM_);
    transw<<<dim3(DIM_ / 32, DIM_ / 32), 256, 0, stream>>>(wout, woutT, DIM_);

    dim3 g1(NTOT_ / 128, M_ / 128);         // (32,16)
    gemm_in_mfma<<<g1, 256, 0, stream>>>(xb, wT, qp, kp, vp, gt);

    dim3 gs(NC_, H_, B_);                   // (16,16,2)
    chunk_state<<<gs, 256, 0, stream>>>(kp, vp, S, ksum);

    dim3 gp(H_, B_);                        // (16,2)
    prefix_state<<<gp, 256, 0, stream>>>(S, ksum);

    attn_out<<<gs, 256, 0, stream>>>(qp, kp, vp, S, ksum, gt, att_b);

    dim3 g3(DIM_ / 128, M_ / 128);          // (8,16)
    gemm_out_mfma<<<g3, 256, 0, stream>>>(att_b, woutT, out);
}

// Round 8
// 106.608 us; speedup vs baseline: 13.2300x; 1.3909x over previous
//
#include <hip/hip_runtime.h>
#include <hip/hip_bf16.h>
#include <math.h>

#define B_    2
#define T_    1024
#define DIM_  1024
#define H_    16
#define D_    64
#define M_    (B_ * T_)      // 2048 rows
#define NQKV_ 3072
#define NTOT_ 4096
#define NC_   16             // chunks of 64 along T

typedef __attribute__((ext_vector_type(8))) short short8v;   // 8 bf16
typedef __attribute__((ext_vector_type(4))) short short4v;   // 4 bf16
typedef __attribute__((ext_vector_type(4))) float floatx4;

__device__ __forceinline__ float elu1(float x) {
    return x > 0.f ? x + 1.f : expf(x);
}
__device__ __forceinline__ unsigned short f2bf(float f) {
    unsigned int u = __float_as_uint(f);
    return (unsigned short)((u + 0x7FFFu + ((u >> 16) & 1u)) >> 16);   // RNE
}
__device__ __forceinline__ float bf2f(unsigned short s) {
    return __uint_as_float((unsigned int)s << 16);
}
// chunk-permutation used by the big-GEMM core (2-way max aliasing = free)
__device__ __forceinline__ int swz(int r) { return (r & 3) ^ ((r >> 2) & 1); }
// XOR-swizzled byte offset within a [rows][64]bf16 LDS tile (128B rows):
// spreads the 16-rows-same-column fragment read across 8 bank slots.
__device__ __forceinline__ int swzb(int row, int byte) {
    return row * 128 + (byte ^ ((row & 7) << 4));
}

// ---------------------------------------------------------------------------
// pre-pass: cast x f32 -> bf16 (8 elems/thread)
// ---------------------------------------------------------------------------
__global__ __launch_bounds__(256) void cast_x(
    const float* __restrict__ src, unsigned short* __restrict__ dst) {
    int i = blockIdx.x * 256 + threadIdx.x;
    float4 v0 = ((const float4*)src)[i * 2];
    float4 v1 = ((const float4*)src)[i * 2 + 1];
    short8v o;
    o[0]=f2bf(v0.x); o[1]=f2bf(v0.y); o[2]=f2bf(v0.z); o[3]=f2bf(v0.w);
    o[4]=f2bf(v1.x); o[5]=f2bf(v1.y); o[6]=f2bf(v1.z); o[7]=f2bf(v1.w);
    *(short8v*)&dst[(size_t)i * 8] = o;
}

// ---------------------------------------------------------------------------
// pre-pass: transpose+cast weight (K=1024, srcN) f32 row-major -> bf16 [N][1024]
// ---------------------------------------------------------------------------
__global__ __launch_bounds__(256) void transw(
    const float* __restrict__ src, unsigned short* __restrict__ dst, int srcN) {
    __shared__ float t[32][33];
    const int n0 = blockIdx.x * 32, k0 = blockIdx.y * 32;
    const int tid = threadIdx.x;
    const int r  = tid >> 3;
    const int c4 = (tid & 7) * 4;
    float4 v = *(const float4*)&src[(size_t)(k0 + r) * srcN + n0 + c4];
    t[c4 + 0][r] = v.x; t[c4 + 1][r] = v.y; t[c4 + 2][r] = v.z; t[c4 + 3][r] = v.w;
    __syncthreads();
    short4v o;
    o[0] = f2bf(t[tid >> 3][(tid & 7) * 4 + 0]);
    o[1] = f2bf(t[tid >> 3][(tid & 7) * 4 + 1]);
    o[2] = f2bf(t[tid >> 3][(tid & 7) * 4 + 2]);
    o[3] = f2bf(t[tid >> 3][(tid & 7) * 4 + 3]);
    *(short4v*)&dst[(size_t)(n0 + (tid >> 3)) * 1024 + k0 + (tid & 7) * 4] = o;
}

// ---------------------------------------------------------------------------
// MFMA GEMM core macro: 128x128 tile, BK=32, 4 waves, global_load_lds + swizzle.
// ---------------------------------------------------------------------------
#define GEMM_CORE(A_PTR, BT_PTR)                                               \
    __shared__ short As[128 * 32];                                             \
    __shared__ short Bs[128 * 32];                                             \
    const int tid  = threadIdx.x;                                              \
    const int lane = tid & 63;                                                 \
    const int w    = tid >> 6;                                                 \
    const int wr   = w >> 1, wc = w & 1;                                       \
    const int m0 = blockIdx.y * 128;                                           \
    const int n0 = blockIdx.x * 128;                                           \
    floatx4 acc[4][4];                                                         \
    _Pragma("unroll") for (int i = 0; i < 4; ++i)                              \
        _Pragma("unroll") for (int j = 0; j < 4; ++j)                          \
            acc[i][j] = (floatx4){0.f, 0.f, 0.f, 0.f};                         \
    for (int k0 = 0; k0 < 1024; k0 += 32) {                                    \
        _Pragma("unroll") for (int j = 0; j < 2; ++j) {                        \
            const int r = w * 32 + j * 16 + (lane >> 2);                       \
            const int c = (lane & 3) ^ swz(r);                                 \
            __builtin_amdgcn_global_load_lds(                                  \
                (const __attribute__((address_space(1))) unsigned int*)        \
                    (A_PTR + (size_t)(m0 + r) * 1024 + k0 + c * 8),            \
                (__attribute__((address_space(3))) unsigned int*)              \
                    (&As[(w * 32 + j * 16) * 32]), 16, 0, 0);                  \
            __builtin_amdgcn_global_load_lds(                                  \
                (const __attribute__((address_space(1))) unsigned int*)        \
                    (BT_PTR + (size_t)(n0 + r) * 1024 + k0 + c * 8),           \
                (__attribute__((address_space(3))) unsigned int*)              \
                    (&Bs[(w * 32 + j * 16) * 32]), 16, 0, 0);                  \
        }                                                                      \
        __syncthreads();                                                       \
        short8v af[4], bf[4];                                                  \
        _Pragma("unroll") for (int i = 0; i < 4; ++i) {                        \
            const int ra = wr * 64 + i * 16 + (lane & 15);                     \
            const int ca = (lane >> 4) ^ swz(ra);                              \
            af[i] = *(const short8v*)&As[ra * 32 + ca * 8];                    \
            const int rb = wc * 64 + i * 16 + (lane & 15);                     \
            const int cb = (lane >> 4) ^ swz(rb);                              \
            bf[i] = *(const short8v*)&Bs[rb * 32 + cb * 8];                    \
        }                                                                      \
        _Pragma("unroll") for (int i = 0; i < 4; ++i)                          \
            _Pragma("unroll") for (int j = 0; j < 4; ++j)                      \
                acc[i][j] = __builtin_amdgcn_mfma_f32_16x16x32_bf16(           \
                    af[i], bf[j], acc[i][j], 0, 0, 0);                         \
        __syncthreads();                                                       \
    }

// ---------------------------------------------------------------------------
// Kernel A: fused input GEMM; writes q,k,v as bf16, gate as f32.
// ---------------------------------------------------------------------------
__global__ __launch_bounds__(256) void gemm_in_mfma(
    const unsigned short* __restrict__ xb, const unsigned short* __restrict__ wT,
    unsigned short* __restrict__ qb, unsigned short* __restrict__ kb,
    unsigned short* __restrict__ vb, float* __restrict__ gt) {
    GEMM_CORE(xb, wT)
    const int seg = n0 >> 10;                     // block-uniform: 0 q,1 k,2 v,3 gate
    const int colbase = (n0 & 1023) + wc * 64 + (lane & 15);
#pragma unroll
    for (int i = 0; i < 4; ++i) {
        const int rowb = m0 + wr * 64 + i * 16 + (lane >> 4) * 4;
#pragma unroll
        for (int j = 0; j < 4; ++j) {
            const int col = colbase + j * 16;
#pragma unroll
            for (int r2 = 0; r2 < 4; ++r2) {
                float v = acc[i][j][r2];
                size_t o = (size_t)(rowb + r2) * 1024 + col;
                if (seg == 0)      qb[o] = f2bf(elu1(v));
                else if (seg == 1) kb[o] = f2bf(elu1(v));
                else if (seg == 2) vb[o] = f2bf(v);
                else               gt[o] = 1.f / (1.f + expf(-v));
            }
        }
    }
}

// ---------------------------------------------------------------------------
// Kernel C: output GEMM (bf16 MFMA), plain f32 store.
// ---------------------------------------------------------------------------
__global__ __launch_bounds__(256) void gemm_out_mfma(
    const unsigned short* __restrict__ ab, const unsigned short* __restrict__ wT,
    float* __restrict__ out) {
    GEMM_CORE(ab, wT)
    const int colbase = n0 + wc * 64 + (lane & 15);
#pragma unroll
    for (int i = 0; i < 4; ++i) {
        const int rowb = m0 + wr * 64 + i * 16 + (lane >> 4) * 4;
#pragma unroll
        for (int j = 0; j < 4; ++j) {
#pragma unroll
            for (int r2 = 0; r2 < 4; ++r2)
                out[(size_t)(rowb + r2) * 1024 + colbase + j * 16] = acc[i][j][r2];
        }
    }
}

// ---------------------------------------------------------------------------
// Kernel B1 (MFMA): S_c = K^T V (64x64x64) per (b,h,c); ksum = colsum(K).
// ---------------------------------------------------------------------------
__global__ __launch_bounds__(256) void chunk_state(
    const unsigned short* __restrict__ kb, const unsigned short* __restrict__ vb,
    float* __restrict__ S, float* __restrict__ ksum) {
    __shared__ unsigned short Kt[64 * 64];   // [d][t] swizzled
    __shared__ unsigned short Vt[64 * 64];   // [i][t] swizzled
    const int tid = threadIdx.x;
    const int lane = tid & 63;
    const int w = tid >> 6;
    const int c = blockIdx.x, h = blockIdx.y, b = blockIdx.z;
    const size_t gbase = ((size_t)(b * T_ + c * 64)) * 1024 + h * 64;
    const size_t cb = (size_t)((b * H_ + h) * NC_ + c);

#pragma unroll
    for (int rep = 0; rep < 2; ++rep) {
        int idx = tid + rep * 256;
        int s = idx >> 3, ig = (idx & 7) * 8;
        short8v kv = *(const short8v*)&kb[gbase + (size_t)s * 1024 + ig];
        short8v vv = *(const short8v*)&vb[gbase + (size_t)s * 1024 + ig];
#pragma unroll
        for (int e = 0; e < 8; ++e) {
            *(unsigned short*)((char*)Kt + swzb(ig + e, s * 2)) = (unsigned short)kv[e];
            *(unsigned short*)((char*)Vt + swzb(ig + e, s * 2)) = (unsigned short)vv[e];
        }
    }
    __syncthreads();

    if (tid < 64) {
        float ssum = 0.f;
#pragma unroll
        for (int tb = 0; tb < 8; ++tb) {
            short8v kk = *(const short8v*)((char*)Kt + swzb(tid, tb * 16));
#pragma unroll
            for (int e = 0; e < 8; ++e) ssum += bf2f((unsigned short)kk[e]);
        }
        ksum[cb * 64 + tid] = ssum;
    }

    const int jr  = w * 16 + (lane & 15);
    const int klo = ((lane >> 4) * 8) * 2;   // byte offset of k-slab 0
    short8v a0 = *(const short8v*)((char*)Kt + swzb(jr, klo));
    short8v a1 = *(const short8v*)((char*)Kt + swzb(jr, 64 + klo));
#pragma unroll
    for (int it = 0; it < 4; ++it) {
        const int ir = it * 16 + (lane & 15);
        short8v b0 = *(const short8v*)((char*)Vt + swzb(ir, klo));
        short8v b1 = *(const short8v*)((char*)Vt + swzb(ir, 64 + klo));
        floatx4 a = (floatx4){0.f, 0.f, 0.f, 0.f};
        a = __builtin_amdgcn_mfma_f32_16x16x32_bf16(a0, b0, a, 0, 0, 0);
        a = __builtin_amdgcn_mfma_f32_16x16x32_bf16(a1, b1, a, 0, 0, 0);
#pragma unroll
        for (int r = 0; r < 4; ++r) {
            int j = w * 16 + (lane >> 4) * 4 + r;
            S[cb * 4096 + (size_t)j * 64 + it * 16 + (lane & 15)] = a[r];
        }
    }
}

// ---------------------------------------------------------------------------
// Kernel B2: exclusive prefix over chunks (f32, unchanged)
// ---------------------------------------------------------------------------
__global__ __launch_bounds__(256) void prefix_state(
    float* __restrict__ S, float* __restrict__ ksum) {
    const int tid = threadIdx.x;
    const int h = blockIdx.x, b = blockIdx.y;
    size_t base = (size_t)(b * H_ + h) * NC_ * 4096 + (size_t)tid * 16;
    float acc[16];
#pragma unroll
    for (int i = 0; i < 16; ++i) acc[i] = 0.f;
    for (int c = 0; c < NC_; ++c) {
        size_t o = base + (size_t)c * 4096;
        float t[16];
#pragma unroll
        for (int i4 = 0; i4 < 4; ++i4) {
            float4 v = *(const float4*)&S[o + i4 * 4];
            t[i4*4+0]=v.x; t[i4*4+1]=v.y; t[i4*4+2]=v.z; t[i4*4+3]=v.w;
        }
#pragma unroll
        for (int i4 = 0; i4 < 4; ++i4) {
            float4 w = {acc[i4*4+0], acc[i4*4+1], acc[i4*4+2], acc[i4*4+3]};
            *(float4*)&S[o + i4 * 4] = w;
        }
#pragma unroll
        for (int i = 0; i < 16; ++i) acc[i] += t[i];
    }
    if (tid < 64) {
        size_t kb = (size_t)(b * H_ + h) * NC_ * 64 + tid;
        float a = 0.f;
        for (int c = 0; c < NC_; ++c) {
            float t = ksum[kb + (size_t)c * 64];
            ksum[kb + (size_t)c * 64] = a;
            a += t;
        }
    }
}

// ---------------------------------------------------------------------------
// Kernel B3 (MFMA): scores=QK^T -> mask -> bf16 strip -> num=strip*V + Q*P.
// den folded in via column 64 (V'=ones, P'=kpre). 4 waves; wave w owns t-rows
// [w*16,w*16+16). All LDS fragment reads XOR-swizzled (G4).
// ---------------------------------------------------------------------------
__global__ __launch_bounds__(256) void attn_out(
    const unsigned short* __restrict__ qb, const unsigned short* __restrict__ kb,
    const unsigned short* __restrict__ vb, const float* __restrict__ S,
    const float* __restrict__ ksum, const float* __restrict__ gt,
    unsigned short* __restrict__ att_b) {
    __shared__ unsigned short Qs[64 * 64];    // [t][d]
    __shared__ unsigned short Ks[64 * 64];    // [s][d]
    __shared__ unsigned short Vts[80 * 64];   // [i][s], row64=ones
    __shared__ unsigned short Pts[80 * 64];   // [i][j], row64=kpre
    __shared__ unsigned short Sp[4 * 16 * 64];// per-wave masked-score strips
    const int tid = threadIdx.x;
    const int lane = tid & 63;
    const int w = tid >> 6;
    const int c = blockIdx.x, h = blockIdx.y, b = blockIdx.z;
    const size_t gbase = ((size_t)(b * T_ + c * 64)) * 1024 + h * 64;
    const size_t cb = (size_t)((b * H_ + h) * NC_ + c);

    // stage Q,K row-major (16B swizzled writes)
#pragma unroll
    for (int rep = 0; rep < 2; ++rep) {
        int idx = tid + rep * 256;
        int r = idx >> 3, ig = (idx & 7) * 8;
        short8v qv = *(const short8v*)&qb[gbase + (size_t)r * 1024 + ig];
        short8v kv = *(const short8v*)&kb[gbase + (size_t)r * 1024 + ig];
        *(short8v*)((char*)Qs + swzb(r, ig * 2)) = qv;
        *(short8v*)((char*)Ks + swzb(r, ig * 2)) = kv;
    }
    // stage V transposed
#pragma unroll
    for (int rep = 0; rep < 2; ++rep) {
        int idx = tid + rep * 256;
        int s = idx >> 3, ig = (idx & 7) * 8;
        short8v vv = *(const short8v*)&vb[gbase + (size_t)s * 1024 + ig];
#pragma unroll
        for (int e = 0; e < 8; ++e)
            *(unsigned short*)((char*)Vts + swzb(ig + e, s * 2)) = (unsigned short)vv[e];
    }
    // stage P transposed (f32 -> bf16)
#pragma unroll
    for (int rep = 0; rep < 4; ++rep) {
        int idx = tid + rep * 256;
        int j = idx >> 4, i4 = (idx & 15) * 4;
        float4 pv = *(const float4*)&S[cb * 4096 + (size_t)j * 64 + i4];
        *(unsigned short*)((char*)Pts + swzb(i4 + 0, j * 2)) = f2bf(pv.x);
        *(unsigned short*)((char*)Pts + swzb(i4 + 1, j * 2)) = f2bf(pv.y);
        *(unsigned short*)((char*)Pts + swzb(i4 + 2, j * 2)) = f2bf(pv.z);
        *(unsigned short*)((char*)Pts + swzb(i4 + 3, j * 2)) = f2bf(pv.w);
    }
    // row 64: ones (V') / kpre (P'); rows 65..79: zero
    if (tid < 64) {
        *(unsigned short*)((char*)Vts + swzb(64, tid * 2)) = 0x3F80;
        *(unsigned short*)((char*)Pts + swzb(64, tid * 2)) = f2bf(ksum[cb * 64 + tid]);
    }
    if (tid < 240) {
        int rr = 65 + (tid >> 4), cc = (tid & 15) * 4;
#pragma unroll
        for (int e = 0; e < 4; ++e) {
            *(unsigned short*)((char*)Vts + swzb(rr, (cc + e) * 2)) = 0;
            *(unsigned short*)((char*)Pts + swzb(rr, (cc + e) * 2)) = 0;
        }
    }
    __syncthreads();

    const int t0  = w * 16;
    const int klo = ((lane >> 4) * 8) * 2;
    short8v qa0 = *(const short8v*)((char*)Qs + swzb(t0 + (lane & 15), klo));
    short8v qa1 = *(const short8v*)((char*)Qs + swzb(t0 + (lane & 15), 64 + klo));
    const int tl0 = t0 + (lane >> 4) * 4;    // C-fragment row base (t in chunk)

    // scores = Q K^T, causal mask, bf16 strip to LDS (own-wave region)
#pragma unroll
    for (int jt = 0; jt < 4; ++jt) {
        const int sr = jt * 16 + (lane & 15);
        short8v k0 = *(const short8v*)((char*)Ks + swzb(sr, klo));
        short8v k1 = *(const short8v*)((char*)Ks + swzb(sr, 64 + klo));
        floatx4 sc = (floatx4){0.f, 0.f, 0.f, 0.f};
        sc = __builtin_amdgcn_mfma_f32_16x16x32_bf16(qa0, k0, sc, 0, 0, 0);
        sc = __builtin_amdgcn_mfma_f32_16x16x32_bf16(qa1, k1, sc, 0, 0, 0);
#pragma unroll
        for (int r = 0; r < 4; ++r) {
            float val = (sr <= tl0 + r) ? sc[r] : 0.f;
            *(unsigned short*)((char*)Sp + w * 2048 +
                swzb((lane >> 4) * 4 + r, sr * 2)) = f2bf(val);
        }
    }

    // num = strip @ [V|1] + Q @ [P|kpre]   (5th i-tile col 64 = den)
    short8v sa0 = *(const short8v*)((char*)Sp + w * 2048 + swzb(lane & 15, klo));
    short8v sa1 = *(const short8v*)((char*)Sp + w * 2048 + swzb(lane & 15, 64 + klo));
    floatx4 cn[5];
#pragma unroll
    for (int it = 0; it < 5; ++it) {
        const int ir = it * 16 + (lane & 15);
        short8v bv0 = *(const short8v*)((char*)Vts + swzb(ir, klo));
        short8v bv1 = *(const short8v*)((char*)Vts + swzb(ir, 64 + klo));
        short8v bp0 = *(const short8v*)((char*)Pts + swzb(ir, klo));
        short8v bp1 = *(const short8v*)((char*)Pts + swzb(ir, 64 + klo));
        floatx4 a = (floatx4){0.f, 0.f, 0.f, 0.f};
        a = __builtin_amdgcn_mfma_f32_16x16x32_bf16(sa0, bv0, a, 0, 0, 0);
        a = __builtin_amdgcn_mfma_f32_16x16x32_bf16(sa1, bv1, a, 0, 0, 0);
        a = __builtin_amdgcn_mfma_f32_16x16x32_bf16(qa0, bp0, a, 0, 0, 0);
        a = __builtin_amdgcn_mfma_f32_16x16x32_bf16(qa1, bp1, a, 0, 0, 0);
        cn[it] = a;
    }

    // divide by den (broadcast from col-0 lane of each 16-group), gate, store
#pragma unroll
    for (int r = 0; r < 4; ++r) {
        float den = __shfl(cn[4][r], lane & 48);
        float inv = 1.f / (den + 1e-6f);
        const size_t rowg = gbase + (size_t)(t0 + (lane >> 4) * 4 + r) * 1024;
#pragma unroll
        for (int it = 0; it < 4; ++it) {
            int i = it * 16 + (lane & 15);
            float g = gt[rowg + i];
            att_b[rowg + i] = f2bf(cn[it][r] * inv * g);
        }
    }
}

extern "C" void kernel_launch(void* const* d_in, const int* in_sizes, int n_in,
                              void* d_out, int out_size, void* d_ws, size_t ws_size,
                              hipStream_t stream) {
    const float* x     = (const float*)d_in[0];
    const float* wqkv  = (const float*)d_in[1];
    const float* wgate = (const float*)d_in[2];
    const float* wout  = (const float*)d_in[3];
    float* out = (float*)d_out;

    char* ws = (char*)d_ws;
    unsigned short* xb    = (unsigned short*)(ws + 0);            // 4 MB
    unsigned short* wT    = (unsigned short*)(ws + (4u  << 20));  // 8 MB [4096][1024]
    unsigned short* woutT = (unsigned short*)(ws + (12u << 20));  // 2 MB
    unsigned short* qb    = (unsigned short*)(ws + (14u << 20));  // 4 MB
    unsigned short* kb    = (unsigned short*)(ws + (18u << 20));  // 4 MB
    unsigned short* vb    = (unsigned short*)(ws + (22u << 20));  // 4 MB
    float*          gt    = (float*)(ws + (26u << 20));           // 8 MB
    float*          S     = (float*)(ws + (34u << 20));           // 8 MB
    float*          ksum  = (float*)(ws + (42u << 20));           // 128 KB
    unsigned short* att_b = (unsigned short*)(ws + (43u << 20));  // 4 MB

    cast_x<<<M_ * DIM_ / 8 / 256, 256, 0, stream>>>(x, xb);
    transw<<<dim3(NQKV_ / 32, DIM_ / 32), 256, 0, stream>>>(wqkv, wT, NQKV_);
    transw<<<dim3(DIM_ / 32, DIM_ / 32), 256, 0, stream>>>(wgate, wT + (size_t)NQKV_ * 1024, DIM_);
    transw<<<dim3(DIM_ / 32, DIM_ / 32), 256, 0, stream>>>(wout, woutT, DIM_);

    dim3 g1(NTOT_ / 128, M_ / 128);         // (32,16)
    gemm_in_mfma<<<g1, 256, 0, stream>>>(xb, wT, qb, kb, vb, gt);

    dim3 gs(NC_, H_, B_);                   // (16,16,2)
    chunk_state<<<gs, 256, 0, stream>>>(kb, vb, S, ksum);

    dim3 gp(H_, B_);                        // (16,2)
    prefix_state<<<gp, 256, 0, stream>>>(S, ksum);

    attn_out<<<gs, 256, 0, stream>>>(qb, kb, vb, S, ksum, gt, att_b);

    dim3 g3(DIM_ / 128, M_ / 128);          // (8,16)
    gemm_out_mfma<<<g3, 256, 0, stream>>>(att_b, woutT, out);
}

// Round 9
// 92.048 us; speedup vs baseline: 15.3227x; 1.1582x over previous
//
#include <hip/hip_runtime.h>
#include <hip/hip_bf16.h>
#include <math.h>

#define B_    2
#define T_    1024
#define DIM_  1024
#define H_    16
#define D_    64
#define M_    (B_ * T_)      // 2048 rows
#define NQKV_ 3072
#define NTOT_ 4096
#define NC_   16             // chunks of 64 along T

typedef __attribute__((ext_vector_type(8))) short short8v;   // 8 bf16
typedef __attribute__((ext_vector_type(4))) float floatx4;

__device__ __forceinline__ float elu1(float x) {
    return x > 0.f ? x + 1.f : expf(x);
}
__device__ __forceinline__ unsigned short f2bf(float f) {
    unsigned int u = __float_as_uint(f);
    return (unsigned short)((u + 0x7FFFu + ((u >> 16) & 1u)) >> 16);   // RNE
}
__device__ __forceinline__ float bf2f(unsigned short s) {
    return __uint_as_float((unsigned int)s << 16);
}
// chunk-permutation for the GEMM staging (2-way max aliasing = free)
__device__ __forceinline__ int swz(int r) { return (r & 3) ^ ((r >> 2) & 1); }
// XOR-swizzled byte offset within a [rows][64]bf16 LDS tile (128B rows)
__device__ __forceinline__ int swzb(int row, int byte) {
    return row * 128 + (byte ^ ((row & 7) << 4));
}
__device__ __forceinline__ void glds16(const unsigned short* g, short* l) {
    __builtin_amdgcn_global_load_lds(
        (const __attribute__((address_space(1))) unsigned int*)g,
        (__attribute__((address_space(3))) unsigned int*)l, 16, 0, 0);
}

// ---------------------------------------------------------------------------
// prep: fused cast_x + 3x weight transpose+cast.  Flat grid, role by blockIdx.
// blocks [0,1024): cast x; [1024,4096): wqkv; [4096,5120): wgate; [5120,6144): wout
// ---------------------------------------------------------------------------
__device__ __forceinline__ void transw_body(
    const float* __restrict__ src, unsigned short* __restrict__ dst, int srcN,
    int n0, int k0, float (*t)[33], int tid) {
    const int r  = tid >> 3;
    const int c4 = (tid & 7) * 4;
    float4 v = *(const float4*)&src[(size_t)(k0 + r) * srcN + n0 + c4];
    t[c4 + 0][r] = v.x; t[c4 + 1][r] = v.y; t[c4 + 2][r] = v.z; t[c4 + 3][r] = v.w;
    __syncthreads();
    unsigned short o[4];
    o[0] = f2bf(t[tid >> 3][(tid & 7) * 4 + 0]);
    o[1] = f2bf(t[tid >> 3][(tid & 7) * 4 + 1]);
    o[2] = f2bf(t[tid >> 3][(tid & 7) * 4 + 2]);
    o[3] = f2bf(t[tid >> 3][(tid & 7) * 4 + 3]);
    *(unsigned long long*)&dst[(size_t)(n0 + (tid >> 3)) * 1024 + k0 + (tid & 7) * 4] =
        *(unsigned long long*)o;
}

__global__ __launch_bounds__(256) void prep(
    const float* __restrict__ x, const float* __restrict__ wqkv,
    const float* __restrict__ wgate, const float* __restrict__ wout,
    unsigned short* __restrict__ xb, unsigned short* __restrict__ wT,
    unsigned short* __restrict__ woutT) {
    __shared__ float t[32][33];
    const int blk = blockIdx.x;
    const int tid = threadIdx.x;
    if (blk < 1024) {
        int i = blk * 256 + tid;
        float4 v0 = ((const float4*)x)[i * 2];
        float4 v1 = ((const float4*)x)[i * 2 + 1];
        short8v o;
        o[0]=f2bf(v0.x); o[1]=f2bf(v0.y); o[2]=f2bf(v0.z); o[3]=f2bf(v0.w);
        o[4]=f2bf(v1.x); o[5]=f2bf(v1.y); o[6]=f2bf(v1.z); o[7]=f2bf(v1.w);
        *(short8v*)&xb[(size_t)i * 8] = o;
    } else if (blk < 4096) {
        int l = blk - 1024;
        transw_body(wqkv, wT, 3072, (l % 96) * 32, (l / 96) * 32, t, tid);
    } else if (blk < 5120) {
        int l = blk - 4096;
        transw_body(wgate, wT + (size_t)3072 * 1024, 1024, (l % 32) * 32, (l / 32) * 32, t, tid);
    } else {
        int l = blk - 5120;
        transw_body(wout, woutT, 1024, (l % 32) * 32, (l / 32) * 32, t, tid);
    }
}

// ---------------------------------------------------------------------------
// Kernel A: fused input GEMM, 128x128 tile, BK=32, 2-phase LDS double-buffer.
// ---------------------------------------------------------------------------
__global__ __launch_bounds__(256) void gemm_in_mfma(
    const unsigned short* __restrict__ xb, const unsigned short* __restrict__ wT,
    unsigned short* __restrict__ qb, unsigned short* __restrict__ kb,
    unsigned short* __restrict__ vb, float* __restrict__ gt) {
    __shared__ short As[2][128 * 32];
    __shared__ short Bs[2][128 * 32];
    const int tid  = threadIdx.x;
    const int lane = tid & 63;
    const int w    = tid >> 6;
    const int wr   = w >> 1, wc = w & 1;
    // bijective XCD swizzle (nwg=512, 512%8==0)
    const int bid  = blockIdx.y * 32 + blockIdx.x;
    const int sbid = (bid & 7) * 64 + (bid >> 3);
    const int m0 = (sbid >> 5) * 128;
    const int n0 = (sbid & 31) * 128;

    floatx4 acc[4][4];
#pragma unroll
    for (int i = 0; i < 4; ++i)
#pragma unroll
        for (int j = 0; j < 4; ++j) acc[i][j] = (floatx4){0.f, 0.f, 0.f, 0.f};

#define STAGE_IN(buf, k0)                                                      \
    _Pragma("unroll") for (int j = 0; j < 2; ++j) {                            \
        const int r = w * 32 + j * 16 + (lane >> 2);                           \
        const int c = (lane & 3) ^ swz(r);                                     \
        glds16(xb + (size_t)(m0 + r) * 1024 + (k0) + c * 8,                    \
               &As[buf][(w * 32 + j * 16) * 32]);                              \
        glds16(wT + (size_t)(n0 + r) * 1024 + (k0) + c * 8,                    \
               &Bs[buf][(w * 32 + j * 16) * 32]);                              \
    }

    STAGE_IN(0, 0)
    __syncthreads();
    int cur = 0;
    for (int t = 0; t < 32; ++t) {
        if (t < 31) { STAGE_IN(cur ^ 1, (t + 1) * 32) }
        short8v af[4], bf[4];
#pragma unroll
        for (int i = 0; i < 4; ++i) {
            const int ra = wr * 64 + i * 16 + (lane & 15);
            const int ca = (lane >> 4) ^ swz(ra);
            af[i] = *(const short8v*)&As[cur][ra * 32 + ca * 8];
            const int rb = wc * 64 + i * 16 + (lane & 15);
            const int cb = (lane >> 4) ^ swz(rb);
            bf[i] = *(const short8v*)&Bs[cur][rb * 32 + cb * 8];
        }
#pragma unroll
        for (int i = 0; i < 4; ++i)
#pragma unroll
            for (int j = 0; j < 4; ++j)
                acc[i][j] = __builtin_amdgcn_mfma_f32_16x16x32_bf16(
                    af[i], bf[j], acc[i][j], 0, 0, 0);
        __syncthreads();
        cur ^= 1;
    }

    const int seg = n0 >> 10;                 // block-uniform: 0 q,1 k,2 v,3 gate
    const int colbase = (n0 & 1023) + wc * 64 + (lane & 15);
#pragma unroll
    for (int i = 0; i < 4; ++i) {
        const int rowb = m0 + wr * 64 + i * 16 + (lane >> 4) * 4;
#pragma unroll
        for (int j = 0; j < 4; ++j) {
            const int col = colbase + j * 16;
#pragma unroll
            for (int r2 = 0; r2 < 4; ++r2) {
                float v = acc[i][j][r2];
                size_t o = (size_t)(rowb + r2) * 1024 + col;
                if (seg == 0)      qb[o] = f2bf(elu1(v));
                else if (seg == 1) kb[o] = f2bf(elu1(v));
                else if (seg == 2) vb[o] = f2bf(v);
                else               gt[o] = 1.f / (1.f + expf(-v));
            }
        }
    }
}

// ---------------------------------------------------------------------------
// Kernel C: output GEMM, 64x128 tile (grid 256 blocks), 2-phase dbuf.
// ---------------------------------------------------------------------------
__global__ __launch_bounds__(256) void gemm_out_mfma(
    const unsigned short* __restrict__ ab, const unsigned short* __restrict__ wT,
    float* __restrict__ out) {
    __shared__ short As[2][64 * 32];
    __shared__ short Bs[2][128 * 32];
    const int tid  = threadIdx.x;
    const int lane = tid & 63;
    const int w    = tid >> 6;
    const int wrl  = w >> 1, wcl = w & 1;
    const int bid  = blockIdx.y * 8 + blockIdx.x;          // grid (8,32)
    const int sbid = (bid & 7) * 32 + (bid >> 3);
    const int m0 = (sbid >> 3) * 64;
    const int n0 = (sbid & 7) * 128;

    floatx4 acc[2][4];
#pragma unroll
    for (int i = 0; i < 2; ++i)
#pragma unroll
        for (int j = 0; j < 4; ++j) acc[i][j] = (floatx4){0.f, 0.f, 0.f, 0.f};

#define STAGE_OUT(buf, k0)                                                     \
    {                                                                          \
        const int rA = w * 16 + (lane >> 2);                                   \
        const int cA = (lane & 3) ^ swz(rA);                                   \
        glds16(ab + (size_t)(m0 + rA) * 1024 + (k0) + cA * 8,                  \
               &As[buf][(w * 16) * 32]);                                       \
        _Pragma("unroll") for (int j = 0; j < 2; ++j) {                        \
            const int rB = w * 32 + j * 16 + (lane >> 2);                      \
            const int cB = (lane & 3) ^ swz(rB);                               \
            glds16(wT + (size_t)(n0 + rB) * 1024 + (k0) + cB * 8,              \
                   &Bs[buf][(w * 32 + j * 16) * 32]);                          \
        }                                                                      \
    }

    STAGE_OUT(0, 0)
    __syncthreads();
    int cur = 0;
    for (int t = 0; t < 32; ++t) {
        if (t < 31) { STAGE_OUT(cur ^ 1, (t + 1) * 32) }
        short8v af[2], bf[4];
#pragma unroll
        for (int i = 0; i < 2; ++i) {
            const int ra = wrl * 32 + i * 16 + (lane & 15);
            const int ca = (lane >> 4) ^ swz(ra);
            af[i] = *(const short8v*)&As[cur][ra * 32 + ca * 8];
        }
#pragma unroll
        for (int j = 0; j < 4; ++j) {
            const int rb = wcl * 64 + j * 16 + (lane & 15);
            const int cb = (lane >> 4) ^ swz(rb);
            bf[j] = *(const short8v*)&Bs[cur][rb * 32 + cb * 8];
        }
#pragma unroll
        for (int i = 0; i < 2; ++i)
#pragma unroll
            for (int j = 0; j < 4; ++j)
                acc[i][j] = __builtin_amdgcn_mfma_f32_16x16x32_bf16(
                    af[i], bf[j], acc[i][j], 0, 0, 0);
        __syncthreads();
        cur ^= 1;
    }

    const int colbase = n0 + wcl * 64 + (lane & 15);
#pragma unroll
    for (int i = 0; i < 2; ++i) {
        const int rowb = m0 + wrl * 32 + i * 16 + (lane >> 4) * 4;
#pragma unroll
        for (int j = 0; j < 4; ++j) {
#pragma unroll
            for (int r2 = 0; r2 < 4; ++r2)
                out[(size_t)(rowb + r2) * 1024 + colbase + j * 16] = acc[i][j][r2];
        }
    }
}

// ---------------------------------------------------------------------------
// Kernel B1 (MFMA): St = (K^T V)^T = V^T K stored bf16 [i][j]; per-chunk
// ksum[j] = colsum(K).  attn_out does the prefix itself.
// ---------------------------------------------------------------------------
__global__ __launch_bounds__(256) void chunk_state(
    const unsigned short* __restrict__ kb, const unsigned short* __restrict__ vb,
    unsigned short* __restrict__ St, float* __restrict__ ksum) {
    __shared__ unsigned short Kt[64 * 64];   // [d][t] swizzled
    __shared__ unsigned short Vt[64 * 64];   // [i][t] swizzled
    const int tid = threadIdx.x;
    const int lane = tid & 63;
    const int w = tid >> 6;
    const int c = blockIdx.x, h = blockIdx.y, b = blockIdx.z;
    const size_t gbase = ((size_t)(b * T_ + c * 64)) * 1024 + h * 64;
    const size_t cb = (size_t)((b * H_ + h) * NC_ + c);

#pragma unroll
    for (int rep = 0; rep < 2; ++rep) {
        int idx = tid + rep * 256;
        int s = idx >> 3, ig = (idx & 7) * 8;
        short8v kv = *(const short8v*)&kb[gbase + (size_t)s * 1024 + ig];
        short8v vv = *(const short8v*)&vb[gbase + (size_t)s * 1024 + ig];
#pragma unroll
        for (int e = 0; e < 8; ++e) {
            *(unsigned short*)((char*)Kt + swzb(ig + e, s * 2)) = (unsigned short)kv[e];
            *(unsigned short*)((char*)Vt + swzb(ig + e, s * 2)) = (unsigned short)vv[e];
        }
    }
    __syncthreads();

    if (tid < 64) {
        float ssum = 0.f;
#pragma unroll
        for (int tb = 0; tb < 8; ++tb) {
            short8v kk = *(const short8v*)((char*)Kt + swzb(tid, tb * 16));
#pragma unroll
            for (int e = 0; e < 8; ++e) ssum += bf2f((unsigned short)kk[e]);
        }
        ksum[cb * 64 + tid] = ssum;
    }

    // S^T[i][j] = sum_t v[t][i] k[t][j]:  A = V^T row i, B = K^T row j
    const int ir  = w * 16 + (lane & 15);
    const int klo = ((lane >> 4) * 8) * 2;
    short8v a0 = *(const short8v*)((char*)Vt + swzb(ir, klo));
    short8v a1 = *(const short8v*)((char*)Vt + swzb(ir, 64 + klo));
#pragma unroll
    for (int jt = 0; jt < 4; ++jt) {
        const int jr = jt * 16 + (lane & 15);
        short8v b0 = *(const short8v*)((char*)Kt + swzb(jr, klo));
        short8v b1 = *(const short8v*)((char*)Kt + swzb(jr, 64 + klo));
        floatx4 a = (floatx4){0.f, 0.f, 0.f, 0.f};
        a = __builtin_amdgcn_mfma_f32_16x16x32_bf16(a0, b0, a, 0, 0, 0);
        a = __builtin_amdgcn_mfma_f32_16x16x32_bf16(a1, b1, a, 0, 0, 0);
#pragma unroll
        for (int r = 0; r < 4; ++r) {
            int irow = w * 16 + (lane >> 4) * 4 + r;
            St[cb * 4096 + (size_t)irow * 64 + jr] = f2bf(a[r]);
        }
    }
}

// ---------------------------------------------------------------------------
// Kernel B3 (MFMA): prefix-fold + scores=QK^T -> mask -> bf16 strip ->
// num=strip*[V|1] + Q*[P|kpre].  den folded via column 64.
// ---------------------------------------------------------------------------
__global__ __launch_bounds__(256) void attn_out(
    const unsigned short* __restrict__ qb, const unsigned short* __restrict__ kb,
    const unsigned short* __restrict__ vb, const unsigned short* __restrict__ St,
    const float* __restrict__ ksum, const float* __restrict__ gt,
    unsigned short* __restrict__ att_b) {
    __shared__ unsigned short Qs[64 * 64];    // [t][d]
    __shared__ unsigned short Ks[64 * 64];    // [s][d]
    __shared__ unsigned short Vts[80 * 64];   // [i][s], row64=ones
    __shared__ unsigned short Pts[80 * 64];   // [i][j], row64=kpre
    __shared__ unsigned short Sp[4 * 16 * 64];
    const int tid = threadIdx.x;
    const int lane = tid & 63;
    const int w = tid >> 6;
    const int c = blockIdx.x, h = blockIdx.y, b = blockIdx.z;
    const size_t gbase = ((size_t)(b * T_ + c * 64)) * 1024 + h * 64;
    const size_t cb0 = (size_t)(b * H_ + h) * NC_;

    // stage Q,K row-major (16B swizzled writes)
#pragma unroll
    for (int rep = 0; rep < 2; ++rep) {
        int idx = tid + rep * 256;
        int r = idx >> 3, ig = (idx & 7) * 8;
        short8v qv = *(const short8v*)&qb[gbase + (size_t)r * 1024 + ig];
        short8v kv = *(const short8v*)&kb[gbase + (size_t)r * 1024 + ig];
        *(short8v*)((char*)Qs + swzb(r, ig * 2)) = qv;
        *(short8v*)((char*)Ks + swzb(r, ig * 2)) = kv;
    }
    // stage V transposed
#pragma unroll
    for (int rep = 0; rep < 2; ++rep) {
        int idx = tid + rep * 256;
        int s = idx >> 3, ig = (idx & 7) * 8;
        short8v vv = *(const short8v*)&vb[gbase + (size_t)s * 1024 + ig];
#pragma unroll
        for (int e = 0; e < 8; ++e)
            *(unsigned short*)((char*)Vts + swzb(ig + e, s * 2)) = (unsigned short)vv[e];
    }
    // prefix-fold P^T = sum_{c'<c} St_{c'}  (bf16 terms, f32 accumulate)
    {
        const int prow = tid >> 2;
        const int pj0  = (tid & 3) * 16;
        float pacc[16];
#pragma unroll
        for (int e = 0; e < 16; ++e) pacc[e] = 0.f;
        for (int cc = 0; cc < c; ++cc) {
            const unsigned short* sp = St + (cb0 + cc) * 4096 + (size_t)prow * 64 + pj0;
            short8v s0 = *(const short8v*)sp;
            short8v s1 = *(const short8v*)(sp + 8);
#pragma unroll
            for (int e = 0; e < 8; ++e) {
                pacc[e]     += bf2f((unsigned short)s0[e]);
                pacc[8 + e] += bf2f((unsigned short)s1[e]);
            }
        }
        unsigned short o[16];
#pragma unroll
        for (int e = 0; e < 16; ++e) o[e] = f2bf(pacc[e]);
        *(short8v*)((char*)Pts + swzb(prow, pj0 * 2))      = *(short8v*)&o[0];
        *(short8v*)((char*)Pts + swzb(prow, pj0 * 2 + 16)) = *(short8v*)&o[8];
    }
    // row 64: ones (V') / kpre prefix (P'); rows 65..79: zero
    if (tid < 64) {
        float kp = 0.f;
        for (int cc = 0; cc < c; ++cc) kp += ksum[(cb0 + cc) * 64 + tid];
        *(unsigned short*)((char*)Vts + swzb(64, tid * 2)) = 0x3F80;
        *(unsigned short*)((char*)Pts + swzb(64, tid * 2)) = f2bf(kp);
    }
    if (tid < 240) {
        int rr = 65 + (tid >> 4), cc2 = (tid & 15) * 4;
#pragma unroll
        for (int e = 0; e < 4; ++e) {
            *(unsigned short*)((char*)Vts + swzb(rr, (cc2 + e) * 2)) = 0;
            *(unsigned short*)((char*)Pts + swzb(rr, (cc2 + e) * 2)) = 0;
        }
    }
    __syncthreads();

    const int t0  = w * 16;
    const int klo = ((lane >> 4) * 8) * 2;
    short8v qa0 = *(const short8v*)((char*)Qs + swzb(t0 + (lane & 15), klo));
    short8v qa1 = *(const short8v*)((char*)Qs + swzb(t0 + (lane & 15), 64 + klo));
    const int tl0 = t0 + (lane >> 4) * 4;

    // scores = Q K^T, causal mask, bf16 strip to LDS
#pragma unroll
    for (int jt = 0; jt < 4; ++jt) {
        const int sr = jt * 16 + (lane & 15);
        short8v k0 = *(const short8v*)((char*)Ks + swzb(sr, klo));
        short8v k1 = *(const short8v*)((char*)Ks + swzb(sr, 64 + klo));
        floatx4 sc = (floatx4){0.f, 0.f, 0.f, 0.f};
        sc = __builtin_amdgcn_mfma_f32_16x16x32_bf16(qa0, k0, sc, 0, 0, 0);
        sc = __builtin_amdgcn_mfma_f32_16x16x32_bf16(qa1, k1, sc, 0, 0, 0);
#pragma unroll
        for (int r = 0; r < 4; ++r) {
            float val = (sr <= tl0 + r) ? sc[r] : 0.f;
            *(unsigned short*)((char*)Sp + w * 2048 +
                swzb((lane >> 4) * 4 + r, sr * 2)) = f2bf(val);
        }
    }

    // num = strip @ [V|1] + Q @ [P|kpre]
    short8v sa0 = *(const short8v*)((char*)Sp + w * 2048 + swzb(lane & 15, klo));
    short8v sa1 = *(const short8v*)((char*)Sp + w * 2048 + swzb(lane & 15, 64 + klo));
    floatx4 cn[5];
#pragma unroll
    for (int it = 0; it < 5; ++it) {
        const int ir = it * 16 + (lane & 15);
        short8v bv0 = *(const short8v*)((char*)Vts + swzb(ir, klo));
        short8v bv1 = *(const short8v*)((char*)Vts + swzb(ir, 64 + klo));
        short8v bp0 = *(const short8v*)((char*)Pts + swzb(ir, klo));
        short8v bp1 = *(const short8v*)((char*)Pts + swzb(ir, 64 + klo));
        floatx4 a = (floatx4){0.f, 0.f, 0.f, 0.f};
        a = __builtin_amdgcn_mfma_f32_16x16x32_bf16(sa0, bv0, a, 0, 0, 0);
        a = __builtin_amdgcn_mfma_f32_16x16x32_bf16(sa1, bv1, a, 0, 0, 0);
        a = __builtin_amdgcn_mfma_f32_16x16x32_bf16(qa0, bp0, a, 0, 0, 0);
        a = __builtin_amdgcn_mfma_f32_16x16x32_bf16(qa1, bp1, a, 0, 0, 0);
        cn[it] = a;
    }

#pragma unroll
    for (int r = 0; r < 4; ++r) {
        float den = __shfl(cn[4][r], lane & 48);
        float inv = 1.f / (den + 1e-6f);
        const size_t rowg = gbase + (size_t)(t0 + (lane >> 4) * 4 + r) * 1024;
#pragma unroll
        for (int it = 0; it < 4; ++it) {
            int i = it * 16 + (lane & 15);
            float g = gt[rowg + i];
            att_b[rowg + i] = f2bf(cn[it][r] * inv * g);
        }
    }
}

extern "C" void kernel_launch(void* const* d_in, const int* in_sizes, int n_in,
                              void* d_out, int out_size, void* d_ws, size_t ws_size,
                              hipStream_t stream) {
    const float* x     = (const float*)d_in[0];
    const float* wqkv  = (const float*)d_in[1];
    const float* wgate = (const float*)d_in[2];
    const float* wout  = (const float*)d_in[3];
    float* out = (float*)d_out;

    char* ws = (char*)d_ws;
    unsigned short* xb    = (unsigned short*)(ws + 0);            // 4 MB
    unsigned short* wT    = (unsigned short*)(ws + (4u  << 20));  // 8 MB [4096][1024]
    unsigned short* woutT = (unsigned short*)(ws + (12u << 20));  // 2 MB
    unsigned short* qb    = (unsigned short*)(ws + (14u << 20));  // 4 MB
    unsigned short* kb    = (unsigned short*)(ws + (18u << 20));  // 4 MB
    unsigned short* vb    = (unsigned short*)(ws + (22u << 20));  // 4 MB
    float*          gt    = (float*)(ws + (26u << 20));           // 8 MB
    unsigned short* St    = (unsigned short*)(ws + (34u << 20));  // 4 MB bf16 S^T
    float*          ksum  = (float*)(ws + (38u << 20));           // 128 KB
    unsigned short* att_b = (unsigned short*)(ws + (39u << 20));  // 4 MB

    prep<<<6144, 256, 0, stream>>>(x, wqkv, wgate, wout, xb, wT, woutT);

    dim3 g1(NTOT_ / 128, M_ / 128);         // (32,16)
    gemm_in_mfma<<<g1, 256, 0, stream>>>(xb, wT, qb, kb, vb, gt);

    dim3 gs(NC_, H_, B_);                   // (16,16,2)
    chunk_state<<<gs, 256, 0, stream>>>(kb, vb, St, ksum);

    attn_out<<<gs, 256, 0, stream>>>(qb, kb, vb, St, ksum, gt, att_b);

    dim3 g3(DIM_ / 128, M_ / 64);           // (8,32)
    gemm_out_mfma<<<g3, 256, 0, stream>>>(att_b, woutT, out);
}

// Round 10
// 79.294 us; speedup vs baseline: 17.7873x; 1.1608x over previous
//
#include <hip/hip_runtime.h>
#include <hip/hip_bf16.h>
#include <math.h>

#define B_    2
#define T_    1024
#define DIM_  1024
#define H_    16
#define D_    64
#define M_    (B_ * T_)      // 2048 rows
#define NQKV_ 3072
#define NTOT_ 4096
#define NC_   16             // chunks of 64 along T

typedef __attribute__((ext_vector_type(8))) short short8v;   // 8 bf16
typedef __attribute__((ext_vector_type(4))) float floatx4;

__device__ __forceinline__ float elu1(float x) {
    return x > 0.f ? x + 1.f : expf(x);
}
__device__ __forceinline__ unsigned short f2bf(float f) {
    unsigned int u = __float_as_uint(f);
    return (unsigned short)((u + 0x7FFFu + ((u >> 16) & 1u)) >> 16);   // RNE
}
__device__ __forceinline__ float bf2f(unsigned short s) {
    return __uint_as_float((unsigned int)s << 16);
}
// XOR-swizzled byte offset within a [rows][64]bf16 LDS tile (128B rows)
__device__ __forceinline__ int swzb(int row, int byte) {
    return row * 128 + (byte ^ ((row & 7) << 4));
}
__device__ __forceinline__ void glds16(const unsigned short* g, short* l) {
    __builtin_amdgcn_global_load_lds(
        (const __attribute__((address_space(1))) unsigned int*)g,
        (__attribute__((address_space(3))) unsigned int*)l, 16, 0, 0);
}

// ---------------------------------------------------------------------------
// prep: fused cast_x + 3x weight transpose+cast.  Flat grid, role by blockIdx.
// ---------------------------------------------------------------------------
__device__ __forceinline__ void transw_body(
    const float* __restrict__ src, unsigned short* __restrict__ dst, int srcN,
    int n0, int k0, float (*t)[33], int tid) {
    const int r  = tid >> 3;
    const int c4 = (tid & 7) * 4;
    float4 v = *(const float4*)&src[(size_t)(k0 + r) * srcN + n0 + c4];
    t[c4 + 0][r] = v.x; t[c4 + 1][r] = v.y; t[c4 + 2][r] = v.z; t[c4 + 3][r] = v.w;
    __syncthreads();
    unsigned short o[4];
    o[0] = f2bf(t[tid >> 3][(tid & 7) * 4 + 0]);
    o[1] = f2bf(t[tid >> 3][(tid & 7) * 4 + 1]);
    o[2] = f2bf(t[tid >> 3][(tid & 7) * 4 + 2]);
    o[3] = f2bf(t[tid >> 3][(tid & 7) * 4 + 3]);
    *(unsigned long long*)&dst[(size_t)(n0 + (tid >> 3)) * 1024 + k0 + (tid & 7) * 4] =
        *(unsigned long long*)o;
}

__global__ __launch_bounds__(256) void prep(
    const float* __restrict__ x, const float* __restrict__ wqkv,
    const float* __restrict__ wgate, const float* __restrict__ wout,
    unsigned short* __restrict__ xb, unsigned short* __restrict__ wT,
    unsigned short* __restrict__ woutT) {
    __shared__ float t[32][33];
    const int blk = blockIdx.x;
    const int tid = threadIdx.x;
    if (blk < 1024) {
        int i = blk * 256 + tid;
        float4 v0 = ((const float4*)x)[i * 2];
        float4 v1 = ((const float4*)x)[i * 2 + 1];
        short8v o;
        o[0]=f2bf(v0.x); o[1]=f2bf(v0.y); o[2]=f2bf(v0.z); o[3]=f2bf(v0.w);
        o[4]=f2bf(v1.x); o[5]=f2bf(v1.y); o[6]=f2bf(v1.z); o[7]=f2bf(v1.w);
        *(short8v*)&xb[(size_t)i * 8] = o;
    } else if (blk < 4096) {
        int l = blk - 1024;
        transw_body(wqkv, wT, 3072, (l % 96) * 32, (l / 96) * 32, t, tid);
    } else if (blk < 5120) {
        int l = blk - 4096;
        transw_body(wgate, wT + (size_t)3072 * 1024, 1024, (l % 32) * 32, (l / 32) * 32, t, tid);
    } else {
        int l = blk - 5120;
        transw_body(wout, woutT, 1024, (l % 32) * 32, (l / 32) * 32, t, tid);
    }
}

// ---------------------------------------------------------------------------
// Kernel A: input GEMM 128x128, BK=64, dbuf LDS, counted vmcnt + raw barriers.
// Per wave per iter: 8 global_load_lds (4 A + 4 B) -> vmcnt(8).
// ---------------------------------------------------------------------------
__global__ __launch_bounds__(256) void gemm_in_mfma(
    const unsigned short* __restrict__ xb, const unsigned short* __restrict__ wT,
    unsigned short* __restrict__ qb, unsigned short* __restrict__ kb,
    unsigned short* __restrict__ vb, unsigned short* __restrict__ gtb) {
    __shared__ short As[2][128 * 64];      // 32 KB
    __shared__ short Bs[2][128 * 64];      // 32 KB
    const int tid  = threadIdx.x;
    const int lane = tid & 63;
    const int w    = tid >> 6;
    const int wr   = w >> 1, wc = w & 1;
    const int m0 = blockIdx.y * 128;
    const int n0 = blockIdx.x * 128;

    floatx4 acc[4][4];
#pragma unroll
    for (int i = 0; i < 4; ++i)
#pragma unroll
        for (int j = 0; j < 4; ++j) acc[i][j] = (floatx4){0.f, 0.f, 0.f, 0.f};

    const int srow = (lane >> 3);          // 0..7 within 8-row group
    const int schk = (lane & 7);           // 16B chunk within row

#define STAGE_IN(buf, k0)                                                      \
    _Pragma("unroll") for (int g = 0; g < 4; ++g) {                            \
        const int r = w * 32 + g * 8 + srow;                                   \
        const int c = schk ^ (r & 7);                                          \
        glds16(xb + (size_t)(m0 + r) * 1024 + (k0) + c * 8,                    \
               &As[buf][(w * 32 + g * 8) * 64]);                               \
        glds16(wT + (size_t)(n0 + r) * 1024 + (k0) + c * 8,                    \
               &Bs[buf][(w * 32 + g * 8) * 64]);                               \
    }

    STAGE_IN(0, 0)
    int cur = 0;
    for (int t = 0; t < 16; ++t) {
        if (t < 15) {
            STAGE_IN(cur ^ 1, (t + 1) * 64)
            asm volatile("s_waitcnt vmcnt(8)\ns_barrier" ::: "memory");
        } else {
            asm volatile("s_waitcnt vmcnt(0)\ns_barrier" ::: "memory");
        }
        short8v af[4][2], bf[4][2];
#pragma unroll
        for (int i = 0; i < 4; ++i) {
            const int ra = wr * 64 + i * 16 + (lane & 15);
            const int rb = wc * 64 + i * 16 + (lane & 15);
#pragma unroll
            for (int kk = 0; kk < 2; ++kk) {
                const int ca = (kk * 4 + (lane >> 4)) ^ (ra & 7);
                const int cb = (kk * 4 + (lane >> 4)) ^ (rb & 7);
                af[i][kk] = *(const short8v*)&As[cur][ra * 64 + ca * 8];
                bf[i][kk] = *(const short8v*)&Bs[cur][rb * 64 + cb * 8];
            }
        }
#pragma unroll
        for (int kk = 0; kk < 2; ++kk)
#pragma unroll
            for (int i = 0; i < 4; ++i)
#pragma unroll
                for (int j = 0; j < 4; ++j)
                    acc[i][j] = __builtin_amdgcn_mfma_f32_16x16x32_bf16(
                        af[i][kk], bf[j][kk], acc[i][j], 0, 0, 0);
        if (t < 15) asm volatile("s_barrier" ::: "memory");
        cur ^= 1;
    }

    const int seg = n0 >> 10;                 // block-uniform: 0 q,1 k,2 v,3 gate
    const int colbase = (n0 & 1023) + wc * 64 + (lane & 15);
#pragma unroll
    for (int i = 0; i < 4; ++i) {
        const int rowb = m0 + wr * 64 + i * 16 + (lane >> 4) * 4;
#pragma unroll
        for (int j = 0; j < 4; ++j) {
            const int col = colbase + j * 16;
#pragma unroll
            for (int r2 = 0; r2 < 4; ++r2) {
                float v = acc[i][j][r2];
                size_t o = (size_t)(rowb + r2) * 1024 + col;
                if (seg == 0)      qb[o] = f2bf(elu1(v));
                else if (seg == 1) kb[o] = f2bf(elu1(v));
                else if (seg == 2) vb[o] = f2bf(v);
                else               gtb[o] = f2bf(1.f / (1.f + expf(-v)));
            }
        }
    }
}

// ---------------------------------------------------------------------------
// Kernel C: output GEMM 64x128, BK=64, dbuf, counted vmcnt(6) + raw barriers.
// ---------------------------------------------------------------------------
__global__ __launch_bounds__(256) void gemm_out_mfma(
    const unsigned short* __restrict__ ab, const unsigned short* __restrict__ wT,
    float* __restrict__ out) {
    __shared__ short As[2][64 * 64];       // 16 KB
    __shared__ short Bs[2][128 * 64];      // 32 KB
    const int tid  = threadIdx.x;
    const int lane = tid & 63;
    const int w    = tid >> 6;
    const int wrl  = w >> 1, wcl = w & 1;
    const int m0 = blockIdx.y * 64;        // grid (8,32)
    const int n0 = blockIdx.x * 128;

    floatx4 acc[2][4];
#pragma unroll
    for (int i = 0; i < 2; ++i)
#pragma unroll
        for (int j = 0; j < 4; ++j) acc[i][j] = (floatx4){0.f, 0.f, 0.f, 0.f};

    const int srow = (lane >> 3);
    const int schk = (lane & 7);

#define STAGE_OUT(buf, k0)                                                     \
    _Pragma("unroll") for (int g = 0; g < 2; ++g) {                            \
        const int r = w * 16 + g * 8 + srow;                                   \
        const int c = schk ^ (r & 7);                                          \
        glds16(ab + (size_t)(m0 + r) * 1024 + (k0) + c * 8,                    \
               &As[buf][(w * 16 + g * 8) * 64]);                               \
    }                                                                          \
    _Pragma("unroll") for (int g = 0; g < 4; ++g) {                            \
        const int r = w * 32 + g * 8 + srow;                                   \
        const int c = schk ^ (r & 7);                                          \
        glds16(wT + (size_t)(n0 + r) * 1024 + (k0) + c * 8,                    \
               &Bs[buf][(w * 32 + g * 8) * 64]);                               \
    }

    STAGE_OUT(0, 0)
    int cur = 0;
    for (int t = 0; t < 16; ++t) {
        if (t < 15) {
            STAGE_OUT(cur ^ 1, (t + 1) * 64)
            asm volatile("s_waitcnt vmcnt(6)\ns_barrier" ::: "memory");
        } else {
            asm volatile("s_waitcnt vmcnt(0)\ns_barrier" ::: "memory");
        }
        short8v af[2][2], bf[4][2];
#pragma unroll
        for (int i = 0; i < 2; ++i) {
            const int ra = wrl * 32 + i * 16 + (lane & 15);
#pragma unroll
            for (int kk = 0; kk < 2; ++kk) {
                const int ca = (kk * 4 + (lane >> 4)) ^ (ra & 7);
                af[i][kk] = *(const short8v*)&As[cur][ra * 64 + ca * 8];
            }
        }
#pragma unroll
        for (int j = 0; j < 4; ++j) {
            const int rb = wcl * 64 + j * 16 + (lane & 15);
#pragma unroll
            for (int kk = 0; kk < 2; ++kk) {
                const int cb = (kk * 4 + (lane >> 4)) ^ (rb & 7);
                bf[j][kk] = *(const short8v*)&Bs[cur][rb * 64 + cb * 8];
            }
        }
#pragma unroll
        for (int kk = 0; kk < 2; ++kk)
#pragma unroll
            for (int i = 0; i < 2; ++i)
#pragma unroll
                for (int j = 0; j < 4; ++j)
                    acc[i][j] = __builtin_amdgcn_mfma_f32_16x16x32_bf16(
                        af[i][kk], bf[j][kk], acc[i][j], 0, 0, 0);
        if (t < 15) asm volatile("s_barrier" ::: "memory");
        cur ^= 1;
    }

    const int colbase = n0 + wcl * 64 + (lane & 15);
#pragma unroll
    for (int i = 0; i < 2; ++i) {
        const int rowb = m0 + wrl * 32 + i * 16 + (lane >> 4) * 4;
#pragma unroll
        for (int j = 0; j < 4; ++j) {
#pragma unroll
            for (int r2 = 0; r2 < 4; ++r2)
                out[(size_t)(rowb + r2) * 1024 + colbase + j * 16] = acc[i][j][r2];
        }
    }
}

// ---------------------------------------------------------------------------
// Kernel B1 (MFMA): St = (K^T V)^T stored bf16 [i][j]; ksum[j] = colsum(K).
// ---------------------------------------------------------------------------
__global__ __launch_bounds__(256) void chunk_state(
    const unsigned short* __restrict__ kb, const unsigned short* __restrict__ vb,
    unsigned short* __restrict__ St, float* __restrict__ ksum) {
    __shared__ unsigned short Kt[64 * 64];   // [d][t] swizzled
    __shared__ unsigned short Vt[64 * 64];   // [i][t] swizzled
    const int tid = threadIdx.x;
    const int lane = tid & 63;
    const int w = tid >> 6;
    const int c = blockIdx.x, h = blockIdx.y, b = blockIdx.z;
    const size_t gbase = ((size_t)(b * T_ + c * 64)) * 1024 + h * 64;
    const size_t cb = (size_t)((b * H_ + h) * NC_ + c);

#pragma unroll
    for (int rep = 0; rep < 2; ++rep) {
        int idx = tid + rep * 256;
        int s = idx >> 3, ig = (idx & 7) * 8;
        short8v kv = *(const short8v*)&kb[gbase + (size_t)s * 1024 + ig];
        short8v vv = *(const short8v*)&vb[gbase + (size_t)s * 1024 + ig];
#pragma unroll
        for (int e = 0; e < 8; ++e) {
            *(unsigned short*)((char*)Kt + swzb(ig + e, s * 2)) = (unsigned short)kv[e];
            *(unsigned short*)((char*)Vt + swzb(ig + e, s * 2)) = (unsigned short)vv[e];
        }
    }
    __syncthreads();

    if (tid < 64) {
        float ssum = 0.f;
#pragma unroll
        for (int tb = 0; tb < 8; ++tb) {
            short8v kk = *(const short8v*)((char*)Kt + swzb(tid, tb * 16));
#pragma unroll
            for (int e = 0; e < 8; ++e) ssum += bf2f((unsigned short)kk[e]);
        }
        ksum[cb * 64 + tid] = ssum;
    }

    const int ir  = w * 16 + (lane & 15);
    const int klo = ((lane >> 4) * 8) * 2;
    short8v a0 = *(const short8v*)((char*)Vt + swzb(ir, klo));
    short8v a1 = *(const short8v*)((char*)Vt + swzb(ir, 64 + klo));
#pragma unroll
    for (int jt = 0; jt < 4; ++jt) {
        const int jr = jt * 16 + (lane & 15);
        short8v b0 = *(const short8v*)((char*)Kt + swzb(jr, klo));
        short8v b1 = *(const short8v*)((char*)Kt + swzb(jr, 64 + klo));
        floatx4 a = (floatx4){0.f, 0.f, 0.f, 0.f};
        a = __builtin_amdgcn_mfma_f32_16x16x32_bf16(a0, b0, a, 0, 0, 0);
        a = __builtin_amdgcn_mfma_f32_16x16x32_bf16(a1, b1, a, 0, 0, 0);
#pragma unroll
        for (int r = 0; r < 4; ++r) {
            int irow = w * 16 + (lane >> 4) * 4 + r;
            St[cb * 4096 + (size_t)irow * 64 + jr] = f2bf(a[r]);
        }
    }
}

// ---------------------------------------------------------------------------
// Kernel B3 (MFMA): prefix-fold + scores=QK^T -> mask -> bf16 strip ->
// num=strip*[V|1] + Q*[P|kpre].  den folded via column 64.
// ---------------------------------------------------------------------------
__global__ __launch_bounds__(256) void attn_out(
    const unsigned short* __restrict__ qb, const unsigned short* __restrict__ kb,
    const unsigned short* __restrict__ vb, const unsigned short* __restrict__ St,
    const float* __restrict__ ksum, const unsigned short* __restrict__ gtb,
    unsigned short* __restrict__ att_b) {
    __shared__ unsigned short Qs[64 * 64];    // [t][d]
    __shared__ unsigned short Ks[64 * 64];    // [s][d]
    __shared__ unsigned short Vts[80 * 64];   // [i][s], row64=ones
    __shared__ unsigned short Pts[80 * 64];   // [i][j], row64=kpre
    __shared__ unsigned short Sp[4 * 16 * 64];
    const int tid = threadIdx.x;
    const int lane = tid & 63;
    const int w = tid >> 6;
    const int c = blockIdx.x, h = blockIdx.y, b = blockIdx.z;
    const size_t gbase = ((size_t)(b * T_ + c * 64)) * 1024 + h * 64;
    const size_t cb0 = (size_t)(b * H_ + h) * NC_;

#pragma unroll
    for (int rep = 0; rep < 2; ++rep) {
        int idx = tid + rep * 256;
        int r = idx >> 3, ig = (idx & 7) * 8;
        short8v qv = *(const short8v*)&qb[gbase + (size_t)r * 1024 + ig];
        short8v kv = *(const short8v*)&kb[gbase + (size_t)r * 1024 + ig];
        *(short8v*)((char*)Qs + swzb(r, ig * 2)) = qv;
        *(short8v*)((char*)Ks + swzb(r, ig * 2)) = kv;
    }
#pragma unroll
    for (int rep = 0; rep < 2; ++rep) {
        int idx = tid + rep * 256;
        int s = idx >> 3, ig = (idx & 7) * 8;
        short8v vv = *(const short8v*)&vb[gbase + (size_t)s * 1024 + ig];
#pragma unroll
        for (int e = 0; e < 8; ++e)
            *(unsigned short*)((char*)Vts + swzb(ig + e, s * 2)) = (unsigned short)vv[e];
    }
    // prefix-fold P^T = sum_{c'<c} St_{c'}  (bf16 terms, f32 accumulate)
    {
        const int prow = tid >> 2;
        const int pj0  = (tid & 3) * 16;
        float pacc[16];
#pragma unroll
        for (int e = 0; e < 16; ++e) pacc[e] = 0.f;
        for (int cc = 0; cc < c; ++cc) {
            const unsigned short* sp = St + (cb0 + cc) * 4096 + (size_t)prow * 64 + pj0;
            short8v s0 = *(const short8v*)sp;
            short8v s1 = *(const short8v*)(sp + 8);
#pragma unroll
            for (int e = 0; e < 8; ++e) {
                pacc[e]     += bf2f((unsigned short)s0[e]);
                pacc[8 + e] += bf2f((unsigned short)s1[e]);
            }
        }
        unsigned short o[16];
#pragma unroll
        for (int e = 0; e < 16; ++e) o[e] = f2bf(pacc[e]);
        *(short8v*)((char*)Pts + swzb(prow, pj0 * 2))      = *(short8v*)&o[0];
        *(short8v*)((char*)Pts + swzb(prow, pj0 * 2 + 16)) = *(short8v*)&o[8];
    }
    if (tid < 64) {
        float kp = 0.f;
        for (int cc = 0; cc < c; ++cc) kp += ksum[(cb0 + cc) * 64 + tid];
        *(unsigned short*)((char*)Vts + swzb(64, tid * 2)) = 0x3F80;
        *(unsigned short*)((char*)Pts + swzb(64, tid * 2)) = f2bf(kp);
    }
    if (tid < 240) {
        int rr = 65 + (tid >> 4), cc2 = (tid & 15) * 4;
#pragma unroll
        for (int e = 0; e < 4; ++e) {
            *(unsigned short*)((char*)Vts + swzb(rr, (cc2 + e) * 2)) = 0;
            *(unsigned short*)((char*)Pts + swzb(rr, (cc2 + e) * 2)) = 0;
        }
    }
    __syncthreads();

    const int t0  = w * 16;
    const int klo = ((lane >> 4) * 8) * 2;
    short8v qa0 = *(const short8v*)((char*)Qs + swzb(t0 + (lane & 15), klo));
    short8v qa1 = *(const short8v*)((char*)Qs + swzb(t0 + (lane & 15), 64 + klo));
    const int tl0 = t0 + (lane >> 4) * 4;

#pragma unroll
    for (int jt = 0; jt < 4; ++jt) {
        const int sr = jt * 16 + (lane & 15);
        short8v k0 = *(const short8v*)((char*)Ks + swzb(sr, klo));
        short8v k1 = *(const short8v*)((char*)Ks + swzb(sr, 64 + klo));
        floatx4 sc = (floatx4){0.f, 0.f, 0.f, 0.f};
        sc = __builtin_amdgcn_mfma_f32_16x16x32_bf16(qa0, k0, sc, 0, 0, 0);
        sc = __builtin_amdgcn_mfma_f32_16x16x32_bf16(qa1, k1, sc, 0, 0, 0);
#pragma unroll
        for (int r = 0; r < 4; ++r) {
            float val = (sr <= tl0 + r) ? sc[r] : 0.f;
            *(unsigned short*)((char*)Sp + w * 2048 +
                swzb((lane >> 4) * 4 + r, sr * 2)) = f2bf(val);
        }
    }

    short8v sa0 = *(const short8v*)((char*)Sp + w * 2048 + swzb(lane & 15, klo));
    short8v sa1 = *(const short8v*)((char*)Sp + w * 2048 + swzb(lane & 15, 64 + klo));
    floatx4 cn[5];
#pragma unroll
    for (int it = 0; it < 5; ++it) {
        const int ir = it * 16 + (lane & 15);
        short8v bv0 = *(const short8v*)((char*)Vts + swzb(ir, klo));
        short8v bv1 = *(const short8v*)((char*)Vts + swzb(ir, 64 + klo));
        short8v bp0 = *(const short8v*)((char*)Pts + swzb(ir, klo));
        short8v bp1 = *(const short8v*)((char*)Pts + swzb(ir, 64 + klo));
        floatx4 a = (floatx4){0.f, 0.f, 0.f, 0.f};
        a = __builtin_amdgcn_mfma_f32_16x16x32_bf16(sa0, bv0, a, 0, 0, 0);
        a = __builtin_amdgcn_mfma_f32_16x16x32_bf16(sa1, bv1, a, 0, 0, 0);
        a = __builtin_amdgcn_mfma_f32_16x16x32_bf16(qa0, bp0, a, 0, 0, 0);
        a = __builtin_amdgcn_mfma_f32_16x16x32_bf16(qa1, bp1, a, 0, 0, 0);
        cn[it] = a;
    }

#pragma unroll
    for (int r = 0; r < 4; ++r) {
        float den = __shfl(cn[4][r], lane & 48);
        float inv = 1.f / (den + 1e-6f);
        const size_t rowg = gbase + (size_t)(t0 + (lane >> 4) * 4 + r) * 1024;
#pragma unroll
        for (int it = 0; it < 4; ++it) {
            int i = it * 16 + (lane & 15);
            float g = bf2f(gtb[rowg + i]);
            att_b[rowg + i] = f2bf(cn[it][r] * inv * g);
        }
    }
}

extern "C" void kernel_launch(void* const* d_in, const int* in_sizes, int n_in,
                              void* d_out, int out_size, void* d_ws, size_t ws_size,
                              hipStream_t stream) {
    const float* x     = (const float*)d_in[0];
    const float* wqkv  = (const float*)d_in[1];
    const float* wgate = (const float*)d_in[2];
    const float* wout  = (const float*)d_in[3];
    float* out = (float*)d_out;

    char* ws = (char*)d_ws;
    unsigned short* xb    = (unsigned short*)(ws + 0);            // 4 MB
    unsigned short* wT    = (unsigned short*)(ws + (4u  << 20));  // 8 MB
    unsigned short* woutT = (unsigned short*)(ws + (12u << 20));  // 2 MB
    unsigned short* qb    = (unsigned short*)(ws + (14u << 20));  // 4 MB
    unsigned short* kb    = (unsigned short*)(ws + (18u << 20));  // 4 MB
    unsigned short* vb    = (unsigned short*)(ws + (22u << 20));  // 4 MB
    unsigned short* gtb   = (unsigned short*)(ws + (26u << 20));  // 4 MB
    unsigned short* St    = (unsigned short*)(ws + (30u << 20));  // 4 MB
    float*          ksum  = (float*)(ws + (34u << 20));           // 128 KB
    unsigned short* att_b = (unsigned short*)(ws + (35u << 20));  // 4 MB

    prep<<<6144, 256, 0, stream>>>(x, wqkv, wgate, wout, xb, wT, woutT);

    dim3 g1(NTOT_ / 128, M_ / 128);         // (32,16)
    gemm_in_mfma<<<g1, 256, 0, stream>>>(xb, wT, qb, kb, vb, gtb);

    dim3 gs(NC_, H_, B_);                   // (16,16,2)
    chunk_state<<<gs, 256, 0, stream>>>(kb, vb, St, ksum);

    attn_out<<<gs, 256, 0, stream>>>(qb, kb, vb, St, ksum, gtb, att_b);

    dim3 g3(DIM_ / 128, M_ / 64);           // (8,32)
    gemm_out_mfma<<<g3, 256, 0, stream>>>(att_b, woutT, out);
}

// Round 11
// 72.680 us; speedup vs baseline: 19.4061x; 1.0910x over previous
//
#include <hip/hip_runtime.h>
#include <hip/hip_bf16.h>
#include <math.h>

#define B_    2
#define T_    1024
#define DIM_  1024
#define H_    16
#define D_    64
#define M_    (B_ * T_)      // 2048 rows
#define NQKV_ 3072
#define NTOT_ 4096
#define NC_   16             // chunks of 64 along T

typedef __attribute__((ext_vector_type(8))) short short8v;   // 8 bf16
typedef __attribute__((ext_vector_type(4))) float floatx4;

__device__ __forceinline__ float elu1(float x) {
    return x > 0.f ? x + 1.f : expf(x);
}
__device__ __forceinline__ unsigned short f2bf(float f) {
    unsigned int u = __float_as_uint(f);
    return (unsigned short)((u + 0x7FFFu + ((u >> 16) & 1u)) >> 16);   // RNE
}
__device__ __forceinline__ float bf2f(unsigned short s) {
    return __uint_as_float((unsigned int)s << 16);
}
// XOR-swizzled byte offset within a [rows][64]bf16 LDS tile (128B rows)
__device__ __forceinline__ int swzb(int row, int byte) {
    return row * 128 + (byte ^ ((row & 7) << 4));
}
__device__ __forceinline__ void glds16(const unsigned short* g, short* l) {
    __builtin_amdgcn_global_load_lds(
        (const __attribute__((address_space(1))) unsigned int*)g,
        (__attribute__((address_space(3))) unsigned int*)l, 16, 0, 0);
}

// ---------------------------------------------------------------------------
// prep: fused cast_x + 3x weight transpose+cast.  Flat grid, role by blockIdx.
// ---------------------------------------------------------------------------
__device__ __forceinline__ void transw_body(
    const float* __restrict__ src, unsigned short* __restrict__ dst, int srcN,
    int n0, int k0, float (*t)[33], int tid) {
    const int r  = tid >> 3;
    const int c4 = (tid & 7) * 4;
    float4 v = *(const float4*)&src[(size_t)(k0 + r) * srcN + n0 + c4];
    t[c4 + 0][r] = v.x; t[c4 + 1][r] = v.y; t[c4 + 2][r] = v.z; t[c4 + 3][r] = v.w;
    __syncthreads();
    unsigned short o[4];
    o[0] = f2bf(t[tid >> 3][(tid & 7) * 4 + 0]);
    o[1] = f2bf(t[tid >> 3][(tid & 7) * 4 + 1]);
    o[2] = f2bf(t[tid >> 3][(tid & 7) * 4 + 2]);
    o[3] = f2bf(t[tid >> 3][(tid & 7) * 4 + 3]);
    *(unsigned long long*)&dst[(size_t)(n0 + (tid >> 3)) * 1024 + k0 + (tid & 7) * 4] =
        *(unsigned long long*)o;
}

__global__ __launch_bounds__(256) void prep(
    const float* __restrict__ x, const float* __restrict__ wqkv,
    const float* __restrict__ wgate, const float* __restrict__ wout,
    unsigned short* __restrict__ xb, unsigned short* __restrict__ wT,
    unsigned short* __restrict__ woutT) {
    __shared__ float t[32][33];
    const int blk = blockIdx.x;
    const int tid = threadIdx.x;
    if (blk < 1024) {
        int i = blk * 256 + tid;
        float4 v0 = ((const float4*)x)[i * 2];
        float4 v1 = ((const float4*)x)[i * 2 + 1];
        short8v o;
        o[0]=f2bf(v0.x); o[1]=f2bf(v0.y); o[2]=f2bf(v0.z); o[3]=f2bf(v0.w);
        o[4]=f2bf(v1.x); o[5]=f2bf(v1.y); o[6]=f2bf(v1.z); o[7]=f2bf(v1.w);
        *(short8v*)&xb[(size_t)i * 8] = o;
    } else if (blk < 4096) {
        int l = blk - 1024;
        transw_body(wqkv, wT, 3072, (l % 96) * 32, (l / 96) * 32, t, tid);
    } else if (blk < 5120) {
        int l = blk - 4096;
        transw_body(wgate, wT + (size_t)3072 * 1024, 1024, (l % 32) * 32, (l / 32) * 32, t, tid);
    } else {
        int l = blk - 5120;
        transw_body(wout, woutT, 1024, (l % 32) * 32, (l / 32) * 32, t, tid);
    }
}

// ---------------------------------------------------------------------------
// Kernel A: input GEMM 128x128, BK=64, 512 threads (8 waves, 16 waves/CU),
// dbuf LDS, counted vmcnt(4) + raw barriers, setprio around MFMA.
// Wave w owns rows [wr*32,+32) x cols [wc*64,+64), wr=w>>1, wc=w&1.
// ---------------------------------------------------------------------------
__global__ __launch_bounds__(512) void gemm_in_mfma(
    const unsigned short* __restrict__ xb, const unsigned short* __restrict__ wT,
    unsigned short* __restrict__ qb, unsigned short* __restrict__ kb,
    unsigned short* __restrict__ vb, unsigned short* __restrict__ gtb) {
    __shared__ short As[2][128 * 64];      // 32 KB
    __shared__ short Bs[2][128 * 64];      // 32 KB
    const int tid  = threadIdx.x;
    const int lane = tid & 63;
    const int w    = tid >> 6;             // 0..7
    const int wr   = w >> 1, wc = w & 1;
    const int m0 = blockIdx.y * 128;
    const int n0 = blockIdx.x * 128;

    floatx4 acc[2][4];
#pragma unroll
    for (int i = 0; i < 2; ++i)
#pragma unroll
        for (int j = 0; j < 4; ++j) acc[i][j] = (floatx4){0.f, 0.f, 0.f, 0.f};

    const int srow = (lane >> 3);          // 0..7 within 8-row group
    const int schk = (lane & 7);           // 16B chunk within row

#define STAGE_IN(buf, k0)                                                      \
    _Pragma("unroll") for (int g = 0; g < 2; ++g) {                            \
        const int r = w * 16 + g * 8 + srow;                                   \
        const int c = schk ^ (r & 7);                                          \
        glds16(xb + (size_t)(m0 + r) * 1024 + (k0) + c * 8,                    \
               &As[buf][(w * 16 + g * 8) * 64]);                               \
        glds16(wT + (size_t)(n0 + r) * 1024 + (k0) + c * 8,                    \
               &Bs[buf][(w * 16 + g * 8) * 64]);                               \
    }

    STAGE_IN(0, 0)
    int cur = 0;
    for (int t = 0; t < 16; ++t) {
        if (t < 15) {
            STAGE_IN(cur ^ 1, (t + 1) * 64)
            asm volatile("s_waitcnt vmcnt(4)\ns_barrier" ::: "memory");
        } else {
            asm volatile("s_waitcnt vmcnt(0)\ns_barrier" ::: "memory");
        }
        short8v af[2][2], bf[4][2];
#pragma unroll
        for (int i = 0; i < 2; ++i) {
            const int ra = wr * 32 + i * 16 + (lane & 15);
#pragma unroll
            for (int kk = 0; kk < 2; ++kk) {
                const int ca = (kk * 4 + (lane >> 4)) ^ (ra & 7);
                af[i][kk] = *(const short8v*)&As[cur][ra * 64 + ca * 8];
            }
        }
#pragma unroll
        for (int j = 0; j < 4; ++j) {
            const int rb = wc * 64 + j * 16 + (lane & 15);
#pragma unroll
            for (int kk = 0; kk < 2; ++kk) {
                const int cb = (kk * 4 + (lane >> 4)) ^ (rb & 7);
                bf[j][kk] = *(const short8v*)&Bs[cur][rb * 64 + cb * 8];
            }
        }
        __builtin_amdgcn_s_setprio(1);
#pragma unroll
        for (int kk = 0; kk < 2; ++kk)
#pragma unroll
            for (int i = 0; i < 2; ++i)
#pragma unroll
                for (int j = 0; j < 4; ++j)
                    acc[i][j] = __builtin_amdgcn_mfma_f32_16x16x32_bf16(
                        af[i][kk], bf[j][kk], acc[i][j], 0, 0, 0);
        __builtin_amdgcn_s_setprio(0);
        if (t < 15) asm volatile("s_barrier" ::: "memory");
        cur ^= 1;
    }

    const int seg = n0 >> 10;                 // block-uniform: 0 q,1 k,2 v,3 gate
    const int colbase = (n0 & 1023) + wc * 64 + (lane & 15);
#pragma unroll
    for (int i = 0; i < 2; ++i) {
        const int rowb = m0 + wr * 32 + i * 16 + (lane >> 4) * 4;
#pragma unroll
        for (int j = 0; j < 4; ++j) {
            const int col = colbase + j * 16;
#pragma unroll
            for (int r2 = 0; r2 < 4; ++r2) {
                float v = acc[i][j][r2];
                size_t o = (size_t)(rowb + r2) * 1024 + col;
                if (seg == 0)      qb[o] = f2bf(elu1(v));
                else if (seg == 1) kb[o] = f2bf(elu1(v));
                else if (seg == 2) vb[o] = f2bf(v);
                else               gtb[o] = f2bf(1.f / (1.f + expf(-v)));
            }
        }
    }
}

// ---------------------------------------------------------------------------
// Kernel C: output GEMM 64x128, BK=64, dbuf, counted vmcnt(6) + raw barriers.
// ---------------------------------------------------------------------------
__global__ __launch_bounds__(256) void gemm_out_mfma(
    const unsigned short* __restrict__ ab, const unsigned short* __restrict__ wT,
    float* __restrict__ out) {
    __shared__ short As[2][64 * 64];       // 16 KB
    __shared__ short Bs[2][128 * 64];      // 32 KB
    const int tid  = threadIdx.x;
    const int lane = tid & 63;
    const int w    = tid >> 6;
    const int wrl  = w >> 1, wcl = w & 1;
    const int m0 = blockIdx.y * 64;        // grid (8,32)
    const int n0 = blockIdx.x * 128;

    floatx4 acc[2][4];
#pragma unroll
    for (int i = 0; i < 2; ++i)
#pragma unroll
        for (int j = 0; j < 4; ++j) acc[i][j] = (floatx4){0.f, 0.f, 0.f, 0.f};

    const int srow = (lane >> 3);
    const int schk = (lane & 7);

#define STAGE_OUT(buf, k0)                                                     \
    _Pragma("unroll") for (int g = 0; g < 2; ++g) {                            \
        const int r = w * 16 + g * 8 + srow;                                   \
        const int c = schk ^ (r & 7);                                          \
        glds16(ab + (size_t)(m0 + r) * 1024 + (k0) + c * 8,                    \
               &As[buf][(w * 16 + g * 8) * 64]);                               \
    }                                                                          \
    _Pragma("unroll") for (int g = 0; g < 4; ++g) {                            \
        const int r = w * 32 + g * 8 + srow;                                   \
        const int c = schk ^ (r & 7);                                          \
        glds16(wT + (size_t)(n0 + r) * 1024 + (k0) + c * 8,                    \
               &Bs[buf][(w * 32 + g * 8) * 64]);                               \
    }

    STAGE_OUT(0, 0)
    int cur = 0;
    for (int t = 0; t < 16; ++t) {
        if (t < 15) {
            STAGE_OUT(cur ^ 1, (t + 1) * 64)
            asm volatile("s_waitcnt vmcnt(6)\ns_barrier" ::: "memory");
        } else {
            asm volatile("s_waitcnt vmcnt(0)\ns_barrier" ::: "memory");
        }
        short8v af[2][2], bf[4][2];
#pragma unroll
        for (int i = 0; i < 2; ++i) {
            const int ra = wrl * 32 + i * 16 + (lane & 15);
#pragma unroll
            for (int kk = 0; kk < 2; ++kk) {
                const int ca = (kk * 4 + (lane >> 4)) ^ (ra & 7);
                af[i][kk] = *(const short8v*)&As[cur][ra * 64 + ca * 8];
            }
        }
#pragma unroll
        for (int j = 0; j < 4; ++j) {
            const int rb = wcl * 64 + j * 16 + (lane & 15);
#pragma unroll
            for (int kk = 0; kk < 2; ++kk) {
                const int cb = (kk * 4 + (lane >> 4)) ^ (rb & 7);
                bf[j][kk] = *(const short8v*)&Bs[cur][rb * 64 + cb * 8];
            }
        }
        __builtin_amdgcn_s_setprio(1);
#pragma unroll
        for (int kk = 0; kk < 2; ++kk)
#pragma unroll
            for (int i = 0; i < 2; ++i)
#pragma unroll
                for (int j = 0; j < 4; ++j)
                    acc[i][j] = __builtin_amdgcn_mfma_f32_16x16x32_bf16(
                        af[i][kk], bf[j][kk], acc[i][j], 0, 0, 0);
        __builtin_amdgcn_s_setprio(0);
        if (t < 15) asm volatile("s_barrier" ::: "memory");
        cur ^= 1;
    }

    const int colbase = n0 + wcl * 64 + (lane & 15);
#pragma unroll
    for (int i = 0; i < 2; ++i) {
        const int rowb = m0 + wrl * 32 + i * 16 + (lane >> 4) * 4;
#pragma unroll
        for (int j = 0; j < 4; ++j) {
#pragma unroll
            for (int r2 = 0; r2 < 4; ++r2)
                out[(size_t)(rowb + r2) * 1024 + colbase + j * 16] = acc[i][j][r2];
        }
    }
}

// ---------------------------------------------------------------------------
// Kernel B1 (MFMA): St = (K^T V)^T stored bf16 [i][j]; ksum[j] = colsum(K).
// ---------------------------------------------------------------------------
__global__ __launch_bounds__(256) void chunk_state(
    const unsigned short* __restrict__ kb, const unsigned short* __restrict__ vb,
    unsigned short* __restrict__ St, float* __restrict__ ksum) {
    __shared__ unsigned short Kt[64 * 64];   // [d][t] swizzled
    __shared__ unsigned short Vt[64 * 64];   // [i][t] swizzled
    const int tid = threadIdx.x;
    const int lane = tid & 63;
    const int w = tid >> 6;
    const int c = blockIdx.x, h = blockIdx.y, b = blockIdx.z;
    const size_t gbase = ((size_t)(b * T_ + c * 64)) * 1024 + h * 64;
    const size_t cb = (size_t)((b * H_ + h) * NC_ + c);

#pragma unroll
    for (int rep = 0; rep < 2; ++rep) {
        int idx = tid + rep * 256;
        int s = idx >> 3, ig = (idx & 7) * 8;
        short8v kv = *(const short8v*)&kb[gbase + (size_t)s * 1024 + ig];
        short8v vv = *(const short8v*)&vb[gbase + (size_t)s * 1024 + ig];
#pragma unroll
        for (int e = 0; e < 8; ++e) {
            *(unsigned short*)((char*)Kt + swzb(ig + e, s * 2)) = (unsigned short)kv[e];
            *(unsigned short*)((char*)Vt + swzb(ig + e, s * 2)) = (unsigned short)vv[e];
        }
    }
    __syncthreads();

    if (tid < 64) {
        float ssum = 0.f;
#pragma unroll
        for (int tb = 0; tb < 8; ++tb) {
            short8v kk = *(const short8v*)((char*)Kt + swzb(tid, tb * 16));
#pragma unroll
            for (int e = 0; e < 8; ++e) ssum += bf2f((unsigned short)kk[e]);
        }
        ksum[cb * 64 + tid] = ssum;
    }

    const int ir  = w * 16 + (lane & 15);
    const int klo = ((lane >> 4) * 8) * 2;
    short8v a0 = *(const short8v*)((char*)Vt + swzb(ir, klo));
    short8v a1 = *(const short8v*)((char*)Vt + swzb(ir, 64 + klo));
#pragma unroll
    for (int jt = 0; jt < 4; ++jt) {
        const int jr = jt * 16 + (lane & 15);
        short8v b0 = *(const short8v*)((char*)Kt + swzb(jr, klo));
        short8v b1 = *(const short8v*)((char*)Kt + swzb(jr, 64 + klo));
        floatx4 a = (floatx4){0.f, 0.f, 0.f, 0.f};
        a = __builtin_amdgcn_mfma_f32_16x16x32_bf16(a0, b0, a, 0, 0, 0);
        a = __builtin_amdgcn_mfma_f32_16x16x32_bf16(a1, b1, a, 0, 0, 0);
#pragma unroll
        for (int r = 0; r < 4; ++r) {
            int irow = w * 16 + (lane >> 4) * 4 + r;
            St[cb * 4096 + (size_t)irow * 64 + jr] = f2bf(a[r]);
        }
    }
}

// ---------------------------------------------------------------------------
// Kernel B3 (MFMA): prefix-fold + scores=QK^T -> mask -> bf16 strip ->
// num=strip*[V|1] + Q*[P|kpre].  den folded via column 64.
// ---------------------------------------------------------------------------
__global__ __launch_bounds__(256) void attn_out(
    const unsigned short* __restrict__ qb, const unsigned short* __restrict__ kb,
    const unsigned short* __restrict__ vb, const unsigned short* __restrict__ St,
    const float* __restrict__ ksum, const unsigned short* __restrict__ gtb,
    unsigned short* __restrict__ att_b) {
    __shared__ unsigned short Qs[64 * 64];    // [t][d]
    __shared__ unsigned short Ks[64 * 64];    // [s][d]
    __shared__ unsigned short Vts[80 * 64];   // [i][s], row64=ones
    __shared__ unsigned short Pts[80 * 64];   // [i][j], row64=kpre
    __shared__ unsigned short Sp[4 * 16 * 64];
    const int tid = threadIdx.x;
    const int lane = tid & 63;
    const int w = tid >> 6;
    const int c = blockIdx.x, h = blockIdx.y, b = blockIdx.z;
    const size_t gbase = ((size_t)(b * T_ + c * 64)) * 1024 + h * 64;
    const size_t cb0 = (size_t)(b * H_ + h) * NC_;

#pragma unroll
    for (int rep = 0; rep < 2; ++rep) {
        int idx = tid + rep * 256;
        int r = idx >> 3, ig = (idx & 7) * 8;
        short8v qv = *(const short8v*)&qb[gbase + (size_t)r * 1024 + ig];
        short8v kv = *(const short8v*)&kb[gbase + (size_t)r * 1024 + ig];
        *(short8v*)((char*)Qs + swzb(r, ig * 2)) = qv;
        *(short8v*)((char*)Ks + swzb(r, ig * 2)) = kv;
    }
#pragma unroll
    for (int rep = 0; rep < 2; ++rep) {
        int idx = tid + rep * 256;
        int s = idx >> 3, ig = (idx & 7) * 8;
        short8v vv = *(const short8v*)&vb[gbase + (size_t)s * 1024 + ig];
#pragma unroll
        for (int e = 0; e < 8; ++e)
            *(unsigned short*)((char*)Vts + swzb(ig + e, s * 2)) = (unsigned short)vv[e];
    }
    // prefix-fold P^T = sum_{c'<c} St_{c'}  (bf16 terms, f32 accumulate)
    {
        const int prow = tid >> 2;
        const int pj0  = (tid & 3) * 16;
        float pacc[16];
#pragma unroll
        for (int e = 0; e < 16; ++e) pacc[e] = 0.f;
        for (int cc = 0; cc < c; ++cc) {
            const unsigned short* sp = St + (cb0 + cc) * 4096 + (size_t)prow * 64 + pj0;
            short8v s0 = *(const short8v*)sp;
            short8v s1 = *(const short8v*)(sp + 8);
#pragma unroll
            for (int e = 0; e < 8; ++e) {
                pacc[e]     += bf2f((unsigned short)s0[e]);
                pacc[8 + e] += bf2f((unsigned short)s1[e]);
            }
        }
        unsigned short o[16];
#pragma unroll
        for (int e = 0; e < 16; ++e) o[e] = f2bf(pacc[e]);
        *(short8v*)((char*)Pts + swzb(prow, pj0 * 2))      = *(short8v*)&o[0];
        *(short8v*)((char*)Pts + swzb(prow, pj0 * 2 + 16)) = *(short8v*)&o[8];
    }
    if (tid < 64) {
        float kp = 0.f;
        for (int cc = 0; cc < c; ++cc) kp += ksum[(cb0 + cc) * 64 + tid];
        *(unsigned short*)((char*)Vts + swzb(64, tid * 2)) = 0x3F80;
        *(unsigned short*)((char*)Pts + swzb(64, tid * 2)) = f2bf(kp);
    }
    if (tid < 240) {
        int rr = 65 + (tid >> 4), cc2 = (tid & 15) * 4;
#pragma unroll
        for (int e = 0; e < 4; ++e) {
            *(unsigned short*)((char*)Vts + swzb(rr, (cc2 + e) * 2)) = 0;
            *(unsigned short*)((char*)Pts + swzb(rr, (cc2 + e) * 2)) = 0;
        }
    }
    __syncthreads();

    const int t0  = w * 16;
    const int klo = ((lane >> 4) * 8) * 2;
    short8v qa0 = *(const short8v*)((char*)Qs + swzb(t0 + (lane & 15), klo));
    short8v qa1 = *(const short8v*)((char*)Qs + swzb(t0 + (lane & 15), 64 + klo));
    const int tl0 = t0 + (lane >> 4) * 4;

#pragma unroll
    for (int jt = 0; jt < 4; ++jt) {
        const int sr = jt * 16 + (lane & 15);
        short8v k0 = *(const short8v*)((char*)Ks + swzb(sr, klo));
        short8v k1 = *(const short8v*)((char*)Ks + swzb(sr, 64 + klo));
        floatx4 sc = (floatx4){0.f, 0.f, 0.f, 0.f};
        __builtin_amdgcn_s_setprio(1);
        sc = __builtin_amdgcn_mfma_f32_16x16x32_bf16(qa0, k0, sc, 0, 0, 0);
        sc = __builtin_amdgcn_mfma_f32_16x16x32_bf16(qa1, k1, sc, 0, 0, 0);
        __builtin_amdgcn_s_setprio(0);
#pragma unroll
        for (int r = 0; r < 4; ++r) {
            float val = (sr <= tl0 + r) ? sc[r] : 0.f;
            *(unsigned short*)((char*)Sp + w * 2048 +
                swzb((lane >> 4) * 4 + r, sr * 2)) = f2bf(val);
        }
    }

    short8v sa0 = *(const short8v*)((char*)Sp + w * 2048 + swzb(lane & 15, klo));
    short8v sa1 = *(const short8v*)((char*)Sp + w * 2048 + swzb(lane & 15, 64 + klo));
    floatx4 cn[5];
#pragma unroll
    for (int it = 0; it < 5; ++it) {
        const int ir = it * 16 + (lane & 15);
        short8v bv0 = *(const short8v*)((char*)Vts + swzb(ir, klo));
        short8v bv1 = *(const short8v*)((char*)Vts + swzb(ir, 64 + klo));
        short8v bp0 = *(const short8v*)((char*)Pts + swzb(ir, klo));
        short8v bp1 = *(const short8v*)((char*)Pts + swzb(ir, 64 + klo));
        floatx4 a = (floatx4){0.f, 0.f, 0.f, 0.f};
        __builtin_amdgcn_s_setprio(1);
        a = __builtin_amdgcn_mfma_f32_16x16x32_bf16(sa0, bv0, a, 0, 0, 0);
        a = __builtin_amdgcn_mfma_f32_16x16x32_bf16(sa1, bv1, a, 0, 0, 0);
        a = __builtin_amdgcn_mfma_f32_16x16x32_bf16(qa0, bp0, a, 0, 0, 0);
        a = __builtin_amdgcn_mfma_f32_16x16x32_bf16(qa1, bp1, a, 0, 0, 0);
        __builtin_amdgcn_s_setprio(0);
        cn[it] = a;
    }

#pragma unroll
    for (int r = 0; r < 4; ++r) {
        float den = __shfl(cn[4][r], lane & 48);
        float inv = 1.f / (den + 1e-6f);
        const size_t rowg = gbase + (size_t)(t0 + (lane >> 4) * 4 + r) * 1024;
#pragma unroll
        for (int it = 0; it < 4; ++it) {
            int i = it * 16 + (lane & 15);
            float g = bf2f(gtb[rowg + i]);
            att_b[rowg + i] = f2bf(cn[it][r] * inv * g);
        }
    }
}

extern "C" void kernel_launch(void* const* d_in, const int* in_sizes, int n_in,
                              void* d_out, int out_size, void* d_ws, size_t ws_size,
                              hipStream_t stream) {
    const float* x     = (const float*)d_in[0];
    const float* wqkv  = (const float*)d_in[1];
    const float* wgate = (const float*)d_in[2];
    const float* wout  = (const float*)d_in[3];
    float* out = (float*)d_out;

    char* ws = (char*)d_ws;
    unsigned short* xb    = (unsigned short*)(ws + 0);            // 4 MB
    unsigned short* wT    = (unsigned short*)(ws + (4u  << 20));  // 8 MB
    unsigned short* woutT = (unsigned short*)(ws + (12u << 20));  // 2 MB
    unsigned short* qb    = (unsigned short*)(ws + (14u << 20));  // 4 MB
    unsigned short* kb    = (unsigned short*)(ws + (18u << 20));  // 4 MB
    unsigned short* vb    = (unsigned short*)(ws + (22u << 20));  // 4 MB
    unsigned short* gtb   = (unsigned short*)(ws + (26u << 20));  // 4 MB
    unsigned short* St    = (unsigned short*)(ws + (30u << 20));  // 4 MB
    float*          ksum  = (float*)(ws + (34u << 20));           // 128 KB
    unsigned short* att_b = (unsigned short*)(ws + (35u << 20));  // 4 MB

    prep<<<6144, 256, 0, stream>>>(x, wqkv, wgate, wout, xb, wT, woutT);

    dim3 g1(NTOT_ / 128, M_ / 128);         // (32,16)
    gemm_in_mfma<<<g1, 512, 0, stream>>>(xb, wT, qb, kb, vb, gtb);

    dim3 gs(NC_, H_, B_);                   // (16,16,2)
    chunk_state<<<gs, 256, 0, stream>>>(kb, vb, St, ksum);

    attn_out<<<gs, 256, 0, stream>>>(qb, kb, vb, St, ksum, gtb, att_b);

    dim3 g3(DIM_ / 128, M_ / 64);           // (8,32)
    gemm_out_mfma<<<g3, 256, 0, stream>>>(att_b, woutT, out);
}